// Round 4
// baseline (218.480 us; speedup 1.0000x reference)
//
#include <hip/hip_runtime.h>
#include <stdint.h>

#define C 128
#define ALPHA_F 0.1f
#define ONE_MINUS_ALPHA 0.9f
// beta = log(THETA/LAYER + 1) = log(1.25)
#define BETA_F 0.22314355131420976f
#define ONE_MINUS_BETA 0.7768564486857902f

__device__ inline float bf2f(unsigned short u) {
    union { unsigned int i; float f; } c;
    c.i = ((unsigned int)u) << 16;
    return c.f;
}
__device__ inline unsigned short f2bf(float f) {
    union { float f; unsigned int i; } c;
    c.f = f;
    unsigned int r = (c.i + 0x7FFFu + ((c.i >> 16) & 1u)) >> 16;  // RNE
    return (unsigned short)r;
}

// ---------------- counting sort of edges by destination ----------------

__global__ void k_zero(int* __restrict__ cnt, int n) {
    int i = blockIdx.x * blockDim.x + threadIdx.x;
    if (i < n) cnt[i] = 0;
}

__global__ void k_hist(const int* __restrict__ dst, int* __restrict__ cnt, int e) {
    int i = blockIdx.x * blockDim.x + threadIdx.x;
    if (i < e) atomicAdd(&cnt[dst[i]], 1);
}

__global__ __launch_bounds__(256)
void k_scan_a(const int* __restrict__ cnt, int* __restrict__ part, int n) {
    __shared__ int s[256];
    int t = threadIdx.x;
    int i = blockIdx.x * 256 + t;
    s[t] = (i < n) ? cnt[i] : 0;
    __syncthreads();
    for (int off = 128; off > 0; off >>= 1) {
        if (t < off) s[t] += s[t + off];
        __syncthreads();
    }
    if (t == 0) part[blockIdx.x] = s[0];
}

__global__ __launch_bounds__(512)
void k_scan_b(int* __restrict__ part, int np) {
    __shared__ int a[512];
    __shared__ int b[512];
    int t = threadIdx.x;
    a[t] = (t < np) ? part[t] : 0;
    __syncthreads();
    int* cur = a;
    int* nxt = b;
    for (int off = 1; off < 512; off <<= 1) {
        nxt[t] = cur[t] + ((t >= off) ? cur[t - off] : 0);
        __syncthreads();
        int* tmp = cur; cur = nxt; nxt = tmp;
    }
    if (t < np) part[t] = (t > 0) ? cur[t - 1] : 0;  // exclusive
}

__global__ __launch_bounds__(256)
void k_scan_c(const int* __restrict__ cnt, const int* __restrict__ part,
              int* __restrict__ row_ptr, int* __restrict__ cursor,
              float* __restrict__ dinv, int n) {
    __shared__ int a[256];
    __shared__ int b[256];
    int t = threadIdx.x;
    int i = blockIdx.x * 256 + t;
    int v = (i < n) ? cnt[i] : 0;
    a[t] = v;
    __syncthreads();
    int* cur = a;
    int* nxt = b;
    for (int off = 1; off < 256; off <<= 1) {
        nxt[t] = cur[t] + ((t >= off) ? cur[t - off] : 0);
        __syncthreads();
        int* tmp = cur; cur = nxt; nxt = tmp;
    }
    if (i < n) {
        int rp = part[blockIdx.x] + cur[t] - v;
        row_ptr[i] = rp;
        cursor[i]  = rp;
        dinv[i]    = rsqrtf((float)(v + 1));  // deg includes self-loop
    }
}

__global__ void k_place(const int* __restrict__ src, const int* __restrict__ dst,
                        int* __restrict__ cursor, int* __restrict__ sorted_src, int e) {
    int i = blockIdx.x * blockDim.x + threadIdx.x;
    if (i < e) {
        int d = dst[i];
        int pos = atomicAdd(&cursor[d], 1);
        sorted_src[pos] = src[i];
    }
}

// W transpose: Wt[c][j] = W[j][c]
__global__ void k_wt(const float* __restrict__ W, float* __restrict__ Wt) {
    int i = blockIdx.x * 256 + threadIdx.x;
    if (i < C * C) {
        int j = i >> 7;
        int c = i & 127;
        Wt[c * C + j] = W[i];
    }
}

// y[i][:] = bf16(x[i][:] * dinv[i])  -- halves the random-gather bytes
__global__ void k_ybf(const float* __restrict__ x, const float* __restrict__ dinv,
                      unsigned short* __restrict__ y, int n) {
    int t = blockIdx.x * 256 + threadIdx.x;
    int total = n * 32;
    if (t < total) {
        int i = t >> 5;
        float dv = dinv[i];
        float4 v = ((const float4*)x)[t];
        ushort4 o;
        o.x = f2bf(v.x * dv);
        o.y = f2bf(v.y * dv);
        o.z = f2bf(v.z * dv);
        o.w = f2bf(v.w * dv);
        ((ushort4*)y)[t] = o;
    }
}

// ---------------- fused gather + alpha-blend + epilogue GEMM ----------------
// Block = 64 nodes. Phase 1: 4 waves gather 16 nodes each into LDS s-tile
// (half-waves stream even/odd edges, 256 B bf16 rows, merged by shfl_xor(32)).
// Phase 2: 64x128 GEMM from LDS against global Wt (L2-resident), final write.
__global__ __launch_bounds__(256, 4)
void k_fused(const unsigned short* __restrict__ y, const float* __restrict__ x0,
             const int* __restrict__ sorted_src, const int* __restrict__ row_ptr,
             const int* __restrict__ cnt, const float* __restrict__ dinv,
             const float* __restrict__ Wt, const float* __restrict__ bias,
             float* __restrict__ out, int n) {
    __shared__ float st[64][132];

    int tid  = threadIdx.x;
    int w    = tid >> 6;
    int half = (tid >> 5) & 1;
    int l32  = tid & 31;
    int row0 = blockIdx.x * 64;

    const ushort4* y4 = (const ushort4*)y;

    // ---- phase 1: gather ----
    for (int k = 0; k < 16; ++k) {
        int r = w * 16 + k;
        int idx = row0 + r;
        if (idx >= n) {
            if (half == 0) *(float4*)&st[r][4 * l32] = make_float4(0.f, 0.f, 0.f, 0.f);
            continue;
        }
        float dv  = dinv[idx];
        int start = row_ptr[idx];
        int len   = cnt[idx];

        float4 acc = make_float4(0.f, 0.f, 0.f, 0.f);
        int j = half;
        for (; j + 2 < len; j += 4) {
            int s0 = sorted_src[start + j];
            int s1 = sorted_src[start + j + 2];
            ushort4 v0 = y4[(size_t)s0 * 32 + l32];
            ushort4 v1 = y4[(size_t)s1 * 32 + l32];
            acc.x += bf2f(v0.x) + bf2f(v1.x);
            acc.y += bf2f(v0.y) + bf2f(v1.y);
            acc.z += bf2f(v0.z) + bf2f(v1.z);
            acc.w += bf2f(v0.w) + bf2f(v1.w);
        }
        if (j < len) {
            int s0 = sorted_src[start + j];
            ushort4 v0 = y4[(size_t)s0 * 32 + l32];
            acc.x += bf2f(v0.x);
            acc.y += bf2f(v0.y);
            acc.z += bf2f(v0.z);
            acc.w += bf2f(v0.w);
        }
        if (half == 0) {  // self-loop term: + y[idx]
            ushort4 vs = y4[(size_t)idx * 32 + l32];
            acc.x += bf2f(vs.x);
            acc.y += bf2f(vs.y);
            acc.z += bf2f(vs.z);
            acc.w += bf2f(vs.w);
        }

        acc.x += __shfl_xor(acc.x, 32, 64);
        acc.y += __shfl_xor(acc.y, 32, 64);
        acc.z += __shfl_xor(acc.z, 32, 64);
        acc.w += __shfl_xor(acc.w, 32, 64);

        if (half == 0) {
            float4 xv = ((const float4*)x0)[(size_t)idx * 32 + l32];
            float4 s;
            s.x = ONE_MINUS_ALPHA * (dv * acc.x) + ALPHA_F * xv.x;
            s.y = ONE_MINUS_ALPHA * (dv * acc.y) + ALPHA_F * xv.y;
            s.z = ONE_MINUS_ALPHA * (dv * acc.z) + ALPHA_F * xv.z;
            s.w = ONE_MINUS_ALPHA * (dv * acc.w) + ALPHA_F * xv.w;
            *(float4*)&st[r][4 * l32] = s;
        }
    }
    __syncthreads();

    // ---- phase 2: out = (1-beta)*s + beta*(s @ W^T + b) ----
    int tc = tid & 31;
    int tr = tid >> 5;
    const float4* Wt4 = (const float4*)Wt;

    float acc[8][4];
    #pragma unroll
    for (int rr = 0; rr < 8; ++rr)
        #pragma unroll
        for (int jj = 0; jj < 4; ++jj) acc[rr][jj] = 0.f;

    for (int c = 0; c < C; c += 4) {
        float4 w0 = Wt4[(size_t)(c + 0) * 32 + tc];
        float4 w1 = Wt4[(size_t)(c + 1) * 32 + tc];
        float4 w2 = Wt4[(size_t)(c + 2) * 32 + tc];
        float4 w3 = Wt4[(size_t)(c + 3) * 32 + tc];
        #pragma unroll
        for (int rr = 0; rr < 8; ++rr) {
            float4 sr = *(const float4*)&st[8 * tr + rr][c];
            acc[rr][0] += sr.x * w0.x + sr.y * w1.x + sr.z * w2.x + sr.w * w3.x;
            acc[rr][1] += sr.x * w0.y + sr.y * w1.y + sr.z * w2.y + sr.w * w3.y;
            acc[rr][2] += sr.x * w0.z + sr.y * w1.z + sr.z * w2.z + sr.w * w3.z;
            acc[rr][3] += sr.x * w0.w + sr.y * w1.w + sr.z * w2.w + sr.w * w3.w;
        }
    }

    float4 b4 = ((const float4*)bias)[tc];
    #pragma unroll
    for (int rr = 0; rr < 8; ++rr) {
        int r = 8 * tr + rr;
        int grow = row0 + r;
        if (grow < n) {
            float4 sv = *(const float4*)&st[r][4 * tc];
            float4 o;
            o.x = ONE_MINUS_BETA * sv.x + BETA_F * (acc[rr][0] + b4.x);
            o.y = ONE_MINUS_BETA * sv.y + BETA_F * (acc[rr][1] + b4.y);
            o.z = ONE_MINUS_BETA * sv.z + BETA_F * (acc[rr][2] + b4.z);
            o.w = ONE_MINUS_BETA * sv.w + BETA_F * (acc[rr][3] + b4.w);
            ((float4*)(out + (size_t)grow * C))[tc] = o;
        }
    }
}

extern "C" void kernel_launch(void* const* d_in, const int* in_sizes, int n_in,
                              void* d_out, int out_size, void* d_ws, size_t ws_size,
                              hipStream_t stream) {
    const float* x   = (const float*)d_in[0];
    const float* x0  = (const float*)d_in[1];
    const float* W   = (const float*)d_in[2];
    const float* b   = (const float*)d_in[3];
    const int*   ei  = (const int*)d_in[4];

    int n = in_sizes[0] / C;
    int e = in_sizes[4] / 2;
    const int* src = ei;
    const int* dst = ei + e;

    int*   cnt        = (int*)d_ws;
    int*   row_ptr    = cnt + n;
    int*   cursor     = row_ptr + n;
    float* dinv       = (float*)(cursor + n);
    int*   part       = (int*)(dinv + n);
    int*   sorted_src = part + 512;
    float* Wt         = (float*)(sorted_src + e);
    unsigned short* y = (unsigned short*)(Wt + C * C);

    float* out = (float*)d_out;

    int nb = (n + 255) / 256;
    int eb = (e + 255) / 256;

    k_zero  <<<nb, 256, 0, stream>>>(cnt, n);
    k_hist  <<<eb, 256, 0, stream>>>(dst, cnt, e);
    k_wt    <<<(C * C + 255) / 256, 256, 0, stream>>>(W, Wt);
    k_scan_a<<<nb, 256, 0, stream>>>(cnt, part, n);
    k_scan_b<<<1, 512, 0, stream>>>(part, nb);
    k_scan_c<<<nb, 256, 0, stream>>>(cnt, part, row_ptr, cursor, dinv, n);
    k_place <<<eb, 256, 0, stream>>>(src, dst, cursor, sorted_src, e);
    k_ybf   <<<(n * 32 + 255) / 256, 256, 0, stream>>>(x, dinv, y, n);
    k_fused <<<(n + 63) / 64, 256, 0, stream>>>(y, x0, sorted_src, row_ptr, cnt, dinv,
                                                Wt, b, out, n);
}

// Round 5
// 204.793 us; speedup vs baseline: 1.0668x; 1.0668x over previous
//
#include <hip/hip_runtime.h>
#include <stdint.h>

#define C 128
#define ALPHA_F 0.1f
#define ONE_MINUS_ALPHA 0.9f
// beta = log(THETA/LAYER + 1) = log(1.25)
#define BETA_F 0.22314355131420976f
#define ONE_MINUS_BETA 0.7768564486857902f

__device__ inline float bf2f(unsigned short u) {
    union { unsigned int i; float f; } c;
    c.i = ((unsigned int)u) << 16;
    return c.f;
}
__device__ inline unsigned short f2bf(float f) {
    union { float f; unsigned int i; } c;
    c.f = f;
    unsigned int r = (c.i + 0x7FFFu + ((c.i >> 16) & 1u)) >> 16;  // RNE
    return (unsigned short)r;
}

// ---------------- counting sort of edges by destination ----------------

__global__ void k_zero(int* __restrict__ cnt, int n) {
    int i = blockIdx.x * blockDim.x + threadIdx.x;
    if (i < n) cnt[i] = 0;
}

__global__ void k_hist(const int* __restrict__ dst, int* __restrict__ cnt, int e) {
    int i = blockIdx.x * blockDim.x + threadIdx.x;
    if (i < e) atomicAdd(&cnt[dst[i]], 1);
}

__global__ __launch_bounds__(256)
void k_scan_a(const int* __restrict__ cnt, int* __restrict__ part, int n) {
    __shared__ int s[256];
    int t = threadIdx.x;
    int i = blockIdx.x * 256 + t;
    s[t] = (i < n) ? cnt[i] : 0;
    __syncthreads();
    for (int off = 128; off > 0; off >>= 1) {
        if (t < off) s[t] += s[t + off];
        __syncthreads();
    }
    if (t == 0) part[blockIdx.x] = s[0];
}

__global__ __launch_bounds__(512)
void k_scan_b(int* __restrict__ part, int np) {
    __shared__ int a[512];
    __shared__ int b[512];
    int t = threadIdx.x;
    a[t] = (t < np) ? part[t] : 0;
    __syncthreads();
    int* cur = a;
    int* nxt = b;
    for (int off = 1; off < 512; off <<= 1) {
        nxt[t] = cur[t] + ((t >= off) ? cur[t - off] : 0);
        __syncthreads();
        int* tmp = cur; cur = nxt; nxt = tmp;
    }
    if (t < np) part[t] = (t > 0) ? cur[t - 1] : 0;  // exclusive
}

__global__ __launch_bounds__(256)
void k_scan_c(const int* __restrict__ cnt, const int* __restrict__ part,
              int* __restrict__ row_ptr, int* __restrict__ cursor,
              float* __restrict__ dinv, int n) {
    __shared__ int a[256];
    __shared__ int b[256];
    int t = threadIdx.x;
    int i = blockIdx.x * 256 + t;
    int v = (i < n) ? cnt[i] : 0;
    a[t] = v;
    __syncthreads();
    int* cur = a;
    int* nxt = b;
    for (int off = 1; off < 256; off <<= 1) {
        nxt[t] = cur[t] + ((t >= off) ? cur[t - off] : 0);
        __syncthreads();
        int* tmp = cur; cur = nxt; nxt = tmp;
    }
    if (i < n) {
        int rp = part[blockIdx.x] + cur[t] - v;
        row_ptr[i] = rp;
        cursor[i]  = rp;
        dinv[i]    = rsqrtf((float)(v + 1));  // deg includes self-loop
    }
}

__global__ void k_place(const int* __restrict__ src, const int* __restrict__ dst,
                        int* __restrict__ cursor, int* __restrict__ sorted_src, int e) {
    int i = blockIdx.x * blockDim.x + threadIdx.x;
    if (i < e) {
        int d = dst[i];
        int pos = atomicAdd(&cursor[d], 1);
        sorted_src[pos] = src[i];
    }
}

// W transpose: Wt[c][j] = W[j][c]
__global__ void k_wt(const float* __restrict__ W, float* __restrict__ Wt) {
    int i = blockIdx.x * 256 + threadIdx.x;
    if (i < C * C) {
        int j = i >> 7;
        int c = i & 127;
        Wt[c * C + j] = W[i];
    }
}

// y[i][:] = bf16(x[i][:] * dinv[i])  -- 25.6 MB, L2/L3-resident for the gather
__global__ void k_ybf(const float* __restrict__ x, const float* __restrict__ dinv,
                      unsigned short* __restrict__ y, int n) {
    int t = blockIdx.x * 256 + threadIdx.x;
    int total = n * 32;
    if (t < total) {
        int i = t >> 5;
        float dv = dinv[i];
        float4 v = ((const float4*)x)[t];
        ushort4 o;
        o.x = f2bf(v.x * dv);
        o.y = f2bf(v.y * dv);
        o.z = f2bf(v.z * dv);
        o.w = f2bf(v.w * dv);
        ((ushort4*)y)[t] = o;
    }
}

// ---------------- gather + alpha-blend -> sout ----------------
// One wave per node; half-waves stream even/odd edges (32 lanes x ushort4 =
// full 256 B bf16 row), 4 edges in flight per half, merged via shfl_xor(32).
__global__ __launch_bounds__(256)
void k_gather(const unsigned short* __restrict__ y, const float* __restrict__ x0,
              const int* __restrict__ sorted_src, const int* __restrict__ row_ptr,
              const int* __restrict__ cnt, const float* __restrict__ dinv,
              float* __restrict__ sout, int n) {
    int half = (threadIdx.x >> 5) & 1;
    int l32  = threadIdx.x & 31;
    int idx  = blockIdx.x * 4 + (threadIdx.x >> 6);
    if (idx >= n) return;

    const ushort4* y4 = (const ushort4*)y;
    float dv  = dinv[idx];
    int start = row_ptr[idx];
    int len   = cnt[idx];

    float4 acc = make_float4(0.f, 0.f, 0.f, 0.f);

    int j = half;
    for (; j + 6 < len; j += 8) {  // 4 edges in flight for this half
        int s0 = sorted_src[start + j];
        int s1 = sorted_src[start + j + 2];
        int s2 = sorted_src[start + j + 4];
        int s3 = sorted_src[start + j + 6];
        ushort4 v0 = y4[(size_t)s0 * 32 + l32];
        ushort4 v1 = y4[(size_t)s1 * 32 + l32];
        ushort4 v2 = y4[(size_t)s2 * 32 + l32];
        ushort4 v3 = y4[(size_t)s3 * 32 + l32];
        acc.x += (bf2f(v0.x) + bf2f(v1.x)) + (bf2f(v2.x) + bf2f(v3.x));
        acc.y += (bf2f(v0.y) + bf2f(v1.y)) + (bf2f(v2.y) + bf2f(v3.y));
        acc.z += (bf2f(v0.z) + bf2f(v1.z)) + (bf2f(v2.z) + bf2f(v3.z));
        acc.w += (bf2f(v0.w) + bf2f(v1.w)) + (bf2f(v2.w) + bf2f(v3.w));
    }
    for (; j < len; j += 2) {
        int s0 = sorted_src[start + j];
        ushort4 v0 = y4[(size_t)s0 * 32 + l32];
        acc.x += bf2f(v0.x);
        acc.y += bf2f(v0.y);
        acc.z += bf2f(v0.z);
        acc.w += bf2f(v0.w);
    }
    if (half == 0) {  // self-loop term
        ushort4 vs = y4[(size_t)idx * 32 + l32];
        acc.x += bf2f(vs.x);
        acc.y += bf2f(vs.y);
        acc.z += bf2f(vs.z);
        acc.w += bf2f(vs.w);
    }

    acc.x += __shfl_xor(acc.x, 32, 64);
    acc.y += __shfl_xor(acc.y, 32, 64);
    acc.z += __shfl_xor(acc.z, 32, 64);
    acc.w += __shfl_xor(acc.w, 32, 64);

    if (half == 0) {
        float4 xv = ((const float4*)x0)[(size_t)idx * 32 + l32];
        float4 o;
        o.x = ONE_MINUS_ALPHA * (dv * acc.x) + ALPHA_F * xv.x;
        o.y = ONE_MINUS_ALPHA * (dv * acc.y) + ALPHA_F * xv.y;
        o.z = ONE_MINUS_ALPHA * (dv * acc.z) + ALPHA_F * xv.z;
        o.w = ONE_MINUS_ALPHA * (dv * acc.w) + ALPHA_F * xv.w;
        ((float4*)sout)[(size_t)idx * 32 + l32] = o;
    }
}

// ---------------- fused epilogue GEMM ----------------
// out = (1-beta)*s + beta*(s @ W^T + b). s-tile in LDS row-major (33.8 KB ->
// 4 blocks/CU); Wt from global (64 KB, L1/L2-resident). In-place on sout.
__global__ __launch_bounds__(256)
void k_out(const float* __restrict__ sin, const float* __restrict__ Wt,
           const float* __restrict__ bias, float* __restrict__ out, int n) {
    __shared__ float st[64][132];

    int tid = threadIdx.x;
    int row0 = blockIdx.x * 64;

    for (int idx = tid; idx < 64 * 32; idx += 256) {
        int r  = idx >> 5;
        int cq = idx & 31;
        int grow = row0 + r;
        float4 sv = make_float4(0.f, 0.f, 0.f, 0.f);
        if (grow < n) sv = ((const float4*)(sin + (size_t)grow * C))[cq];
        *(float4*)&st[r][4 * cq] = sv;
    }
    __syncthreads();

    int tc = tid & 31;
    int tr = tid >> 5;
    const float4* Wt4 = (const float4*)Wt;

    float acc[8][4];
    #pragma unroll
    for (int rr = 0; rr < 8; ++rr)
        #pragma unroll
        for (int jj = 0; jj < 4; ++jj) acc[rr][jj] = 0.f;

    #pragma unroll 2
    for (int c = 0; c < C; c += 4) {
        float4 w0 = Wt4[(size_t)(c + 0) * 32 + tc];
        float4 w1 = Wt4[(size_t)(c + 1) * 32 + tc];
        float4 w2 = Wt4[(size_t)(c + 2) * 32 + tc];
        float4 w3 = Wt4[(size_t)(c + 3) * 32 + tc];
        #pragma unroll
        for (int rr = 0; rr < 8; ++rr) {
            float4 sr = *(const float4*)&st[8 * tr + rr][c];
            acc[rr][0] += sr.x * w0.x + sr.y * w1.x + sr.z * w2.x + sr.w * w3.x;
            acc[rr][1] += sr.x * w0.y + sr.y * w1.y + sr.z * w2.y + sr.w * w3.y;
            acc[rr][2] += sr.x * w0.z + sr.y * w1.z + sr.z * w2.z + sr.w * w3.z;
            acc[rr][3] += sr.x * w0.w + sr.y * w1.w + sr.z * w2.w + sr.w * w3.w;
        }
    }

    float4 b4 = ((const float4*)bias)[tc];
    #pragma unroll
    for (int rr = 0; rr < 8; ++rr) {
        int r = 8 * tr + rr;
        int grow = row0 + r;
        if (grow < n) {
            float4 sv = *(const float4*)&st[r][4 * tc];
            float4 o;
            o.x = ONE_MINUS_BETA * sv.x + BETA_F * (acc[rr][0] + b4.x);
            o.y = ONE_MINUS_BETA * sv.y + BETA_F * (acc[rr][1] + b4.y);
            o.z = ONE_MINUS_BETA * sv.z + BETA_F * (acc[rr][2] + b4.z);
            o.w = ONE_MINUS_BETA * sv.w + BETA_F * (acc[rr][3] + b4.w);
            ((float4*)(out + (size_t)grow * C))[tc] = o;
        }
    }
}

extern "C" void kernel_launch(void* const* d_in, const int* in_sizes, int n_in,
                              void* d_out, int out_size, void* d_ws, size_t ws_size,
                              hipStream_t stream) {
    const float* x   = (const float*)d_in[0];
    const float* x0  = (const float*)d_in[1];
    const float* W   = (const float*)d_in[2];
    const float* b   = (const float*)d_in[3];
    const int*   ei  = (const int*)d_in[4];

    int n = in_sizes[0] / C;
    int e = in_sizes[4] / 2;
    const int* src = ei;
    const int* dst = ei + e;

    int*   cnt        = (int*)d_ws;
    int*   row_ptr    = cnt + n;
    int*   cursor     = row_ptr + n;
    float* dinv       = (float*)(cursor + n);
    int*   part       = (int*)(dinv + n);
    int*   sorted_src = part + 512;
    float* Wt         = (float*)(sorted_src + e);
    unsigned short* y = (unsigned short*)(Wt + C * C);

    float* sout = (float*)d_out;

    int nb = (n + 255) / 256;
    int eb = (e + 255) / 256;

    k_zero  <<<nb, 256, 0, stream>>>(cnt, n);
    k_hist  <<<eb, 256, 0, stream>>>(dst, cnt, e);
    k_wt    <<<(C * C + 255) / 256, 256, 0, stream>>>(W, Wt);
    k_scan_a<<<nb, 256, 0, stream>>>(cnt, part, n);
    k_scan_b<<<1, 512, 0, stream>>>(part, nb);
    k_scan_c<<<nb, 256, 0, stream>>>(cnt, part, row_ptr, cursor, dinv, n);
    k_place <<<eb, 256, 0, stream>>>(src, dst, cursor, sorted_src, e);
    k_ybf   <<<(n * 32 + 255) / 256, 256, 0, stream>>>(x, dinv, y, n);
    k_gather<<<(n + 3) / 4, 256, 0, stream>>>(y, x0, sorted_src, row_ptr, cnt, dinv, sout, n);
    k_out   <<<(n + 63) / 64, 256, 0, stream>>>(sout, Wt, b, sout, n);
}

// Round 6
// 195.213 us; speedup vs baseline: 1.1192x; 1.0491x over previous
//
#include <hip/hip_runtime.h>
#include <stdint.h>

#define C 128
#define ALPHA_F 0.1f
#define ONE_MINUS_ALPHA 0.9f
// beta = log(THETA/LAYER + 1) = log(1.25)
#define BETA_F 0.22314355131420976f
#define ONE_MINUS_BETA 0.7768564486857902f

__device__ inline float bf2f(unsigned short u) {
    union { unsigned int i; float f; } c;
    c.i = ((unsigned int)u) << 16;
    return c.f;
}
__device__ inline unsigned short f2bf(float f) {
    union { float f; unsigned int i; } c;
    c.f = f;
    unsigned int r = (c.i + 0x7FFFu + ((c.i >> 16) & 1u)) >> 16;  // RNE
    return (unsigned short)r;
}

// ---------------- init: zero cnt + transpose W (merged) ----------------
__global__ void k_init(const float* __restrict__ W, float* __restrict__ Wt,
                       int* __restrict__ cnt, int n) {
    int i = blockIdx.x * 256 + threadIdx.x;
    if (i < n) cnt[i] = 0;
    if (i < C * C) {
        int j = i >> 7;
        int c = i & 127;
        Wt[c * C + j] = W[i];
    }
}

__global__ void k_hist(const int* __restrict__ dst, int* __restrict__ cnt, int e) {
    int i = blockIdx.x * blockDim.x + threadIdx.x;
    if (i < e) atomicAdd(&cnt[dst[i]], 1);
}

__global__ __launch_bounds__(256)
void k_scan_a(const int* __restrict__ cnt, int* __restrict__ part, int n) {
    __shared__ int s[256];
    int t = threadIdx.x;
    int i = blockIdx.x * 256 + t;
    s[t] = (i < n) ? cnt[i] : 0;
    __syncthreads();
    for (int off = 128; off > 0; off >>= 1) {
        if (t < off) s[t] += s[t + off];
        __syncthreads();
    }
    if (t == 0) part[blockIdx.x] = s[0];
}

__global__ __launch_bounds__(512)
void k_scan_b(int* __restrict__ part, int np) {
    __shared__ int a[512];
    __shared__ int b[512];
    int t = threadIdx.x;
    a[t] = (t < np) ? part[t] : 0;
    __syncthreads();
    int* cur = a;
    int* nxt = b;
    for (int off = 1; off < 512; off <<= 1) {
        nxt[t] = cur[t] + ((t >= off) ? cur[t - off] : 0);
        __syncthreads();
        int* tmp = cur; cur = nxt; nxt = tmp;
    }
    if (t < np) part[t] = (t > 0) ? cur[t - 1] : 0;  // exclusive
}

__global__ __launch_bounds__(256)
void k_scan_c(const int* __restrict__ cnt, const int* __restrict__ part,
              int* __restrict__ row_ptr, int* __restrict__ cursor,
              float* __restrict__ dinv, int n) {
    __shared__ int a[256];
    __shared__ int b[256];
    int t = threadIdx.x;
    int i = blockIdx.x * 256 + t;
    int v = (i < n) ? cnt[i] : 0;
    a[t] = v;
    __syncthreads();
    int* cur = a;
    int* nxt = b;
    for (int off = 1; off < 256; off <<= 1) {
        nxt[t] = cur[t] + ((t >= off) ? cur[t - off] : 0);
        __syncthreads();
        int* tmp = cur; cur = nxt; nxt = tmp;
    }
    if (i < n) {
        int rp = part[blockIdx.x] + cur[t] - v;
        row_ptr[i] = rp;
        cursor[i]  = rp;
        dinv[i]    = rsqrtf((float)(v + 1));  // deg includes self-loop
    }
}

__global__ void k_place(const int* __restrict__ src, const int* __restrict__ dst,
                        int* __restrict__ cursor, int* __restrict__ sorted_src, int e) {
    int i = blockIdx.x * blockDim.x + threadIdx.x;
    if (i < e) {
        int d = dst[i];
        int pos = atomicAdd(&cursor[d], 1);
        sorted_src[pos] = src[i];
    }
}

// y[i][:] = bf16(x[i][:] * dinv[i])  -- 25.6 MB, L2/L3-resident for the gather
__global__ void k_ybf(const float* __restrict__ x, const float* __restrict__ dinv,
                      unsigned short* __restrict__ y, int n) {
    int t = blockIdx.x * 256 + threadIdx.x;
    int total = n * 32;
    if (t < total) {
        int i = t >> 5;
        float dv = dinv[i];
        float4 v = ((const float4*)x)[t];
        ushort4 o;
        o.x = f2bf(v.x * dv);
        o.y = f2bf(v.y * dv);
        o.z = f2bf(v.z * dv);
        o.w = f2bf(v.w * dv);
        ((ushort4*)y)[t] = o;
    }
}

// ---------------- gather + alpha-blend -> sout ----------------
// One wave per node. Whole edge list preloaded in one coalesced read (one
// index per lane), broadcast via shfl; half-waves then issue 4 INDEPENDENT
// y-row loads per batch (8 edges/batch wave-wide). Out-of-range slots clamp
// to a duplicate index (L1 hit) with weight 0. Merge halves via shfl_xor(32).
__global__ __launch_bounds__(256)
void k_gather(const unsigned short* __restrict__ y, const float* __restrict__ x0,
              const int* __restrict__ sorted_src, const int* __restrict__ row_ptr,
              const int* __restrict__ cnt, const float* __restrict__ dinv,
              float* __restrict__ sout, int n) {
    int lane = threadIdx.x & 63;
    int half = lane >> 5;
    int l32  = lane & 31;
    int idx  = blockIdx.x * 4 + (threadIdx.x >> 6);
    if (idx >= n) return;

    const ushort4* y4 = (const ushort4*)y;

    // independent front-loads (no mutual deps; compiler issues all early)
    float dv  = dinv[idx];
    int start = row_ptr[idx];
    int len   = cnt[idx];
    float4 xv = ((const float4*)x0)[(size_t)idx * 32 + l32];

    int m = (len < 64) ? len : 64;
    int eidx = (lane < m) ? sorted_src[start + lane] : idx;  // pad = self (valid row)

    float4 acc = make_float4(0.f, 0.f, 0.f, 0.f);

    for (int j = half; j < m; j += 8) {   // 4 edges per half per batch
        bool b1 = (j + 2) < m;
        bool b2 = (j + 4) < m;
        bool b3 = (j + 6) < m;
        int i1 = b1 ? j + 2 : j;
        int i2 = b2 ? j + 4 : j;
        int i3 = b3 ? j + 6 : j;
        int s0 = __shfl(eidx, j, 64);
        int s1 = __shfl(eidx, i1, 64);
        int s2 = __shfl(eidx, i2, 64);
        int s3 = __shfl(eidx, i3, 64);
        ushort4 v0 = y4[(size_t)s0 * 32 + l32];
        ushort4 v1 = y4[(size_t)s1 * 32 + l32];
        ushort4 v2 = y4[(size_t)s2 * 32 + l32];
        ushort4 v3 = y4[(size_t)s3 * 32 + l32];
        float w1 = b1 ? 1.f : 0.f;
        float w2 = b2 ? 1.f : 0.f;
        float w3 = b3 ? 1.f : 0.f;
        acc.x += bf2f(v0.x) + w1 * bf2f(v1.x) + w2 * bf2f(v2.x) + w3 * bf2f(v3.x);
        acc.y += bf2f(v0.y) + w1 * bf2f(v1.y) + w2 * bf2f(v2.y) + w3 * bf2f(v3.y);
        acc.z += bf2f(v0.z) + w1 * bf2f(v1.z) + w2 * bf2f(v2.z) + w3 * bf2f(v3.z);
        acc.w += bf2f(v0.w) + w1 * bf2f(v1.w) + w2 * bf2f(v2.w) + w3 * bf2f(v3.w);
    }

    // rare tail: nodes with more than 64 incident edges
    for (int j = 64 + half; j < len; j += 2) {
        int s0 = sorted_src[start + j];
        ushort4 v0 = y4[(size_t)s0 * 32 + l32];
        acc.x += bf2f(v0.x);
        acc.y += bf2f(v0.y);
        acc.z += bf2f(v0.z);
        acc.w += bf2f(v0.w);
    }

    if (half == 0) {  // self-loop term
        ushort4 vs = y4[(size_t)idx * 32 + l32];
        acc.x += bf2f(vs.x);
        acc.y += bf2f(vs.y);
        acc.z += bf2f(vs.z);
        acc.w += bf2f(vs.w);
    }

    acc.x += __shfl_xor(acc.x, 32, 64);
    acc.y += __shfl_xor(acc.y, 32, 64);
    acc.z += __shfl_xor(acc.z, 32, 64);
    acc.w += __shfl_xor(acc.w, 32, 64);

    if (half == 0) {
        float4 o;
        o.x = ONE_MINUS_ALPHA * (dv * acc.x) + ALPHA_F * xv.x;
        o.y = ONE_MINUS_ALPHA * (dv * acc.y) + ALPHA_F * xv.y;
        o.z = ONE_MINUS_ALPHA * (dv * acc.z) + ALPHA_F * xv.z;
        o.w = ONE_MINUS_ALPHA * (dv * acc.w) + ALPHA_F * xv.w;
        ((float4*)sout)[(size_t)idx * 32 + l32] = o;
    }
}

// ---------------- fused epilogue GEMM ----------------
// out = (1-beta)*s + beta*(s @ W^T + b). s-tile in LDS row-major (33.8 KB ->
// 4 blocks/CU); Wt from global (64 KB, L1/L2-resident). In-place on sout.
__global__ __launch_bounds__(256)
void k_out(const float* __restrict__ sin, const float* __restrict__ Wt,
           const float* __restrict__ bias, float* __restrict__ out, int n) {
    __shared__ float st[64][132];

    int tid = threadIdx.x;
    int row0 = blockIdx.x * 64;

    for (int idx = tid; idx < 64 * 32; idx += 256) {
        int r  = idx >> 5;
        int cq = idx & 31;
        int grow = row0 + r;
        float4 sv = make_float4(0.f, 0.f, 0.f, 0.f);
        if (grow < n) sv = ((const float4*)(sin + (size_t)grow * C))[cq];
        *(float4*)&st[r][4 * cq] = sv;
    }
    __syncthreads();

    int tc = tid & 31;
    int tr = tid >> 5;
    const float4* Wt4 = (const float4*)Wt;

    float acc[8][4];
    #pragma unroll
    for (int rr = 0; rr < 8; ++rr)
        #pragma unroll
        for (int jj = 0; jj < 4; ++jj) acc[rr][jj] = 0.f;

    #pragma unroll 2
    for (int c = 0; c < C; c += 4) {
        float4 w0 = Wt4[(size_t)(c + 0) * 32 + tc];
        float4 w1 = Wt4[(size_t)(c + 1) * 32 + tc];
        float4 w2 = Wt4[(size_t)(c + 2) * 32 + tc];
        float4 w3 = Wt4[(size_t)(c + 3) * 32 + tc];
        #pragma unroll
        for (int rr = 0; rr < 8; ++rr) {
            float4 sr = *(const float4*)&st[8 * tr + rr][c];
            acc[rr][0] += sr.x * w0.x + sr.y * w1.x + sr.z * w2.x + sr.w * w3.x;
            acc[rr][1] += sr.x * w0.y + sr.y * w1.y + sr.z * w2.y + sr.w * w3.y;
            acc[rr][2] += sr.x * w0.z + sr.y * w1.z + sr.z * w2.z + sr.w * w3.z;
            acc[rr][3] += sr.x * w0.w + sr.y * w1.w + sr.z * w2.w + sr.w * w3.w;
        }
    }

    float4 b4 = ((const float4*)bias)[tc];
    #pragma unroll
    for (int rr = 0; rr < 8; ++rr) {
        int r = 8 * tr + rr;
        int grow = row0 + r;
        if (grow < n) {
            float4 sv = *(const float4*)&st[r][4 * tc];
            float4 o;
            o.x = ONE_MINUS_BETA * sv.x + BETA_F * (acc[rr][0] + b4.x);
            o.y = ONE_MINUS_BETA * sv.y + BETA_F * (acc[rr][1] + b4.y);
            o.z = ONE_MINUS_BETA * sv.z + BETA_F * (acc[rr][2] + b4.z);
            o.w = ONE_MINUS_BETA * sv.w + BETA_F * (acc[rr][3] + b4.w);
            ((float4*)(out + (size_t)grow * C))[tc] = o;
        }
    }
}

extern "C" void kernel_launch(void* const* d_in, const int* in_sizes, int n_in,
                              void* d_out, int out_size, void* d_ws, size_t ws_size,
                              hipStream_t stream) {
    const float* x   = (const float*)d_in[0];
    const float* x0  = (const float*)d_in[1];
    const float* W   = (const float*)d_in[2];
    const float* b   = (const float*)d_in[3];
    const int*   ei  = (const int*)d_in[4];

    int n = in_sizes[0] / C;
    int e = in_sizes[4] / 2;
    const int* src = ei;
    const int* dst = ei + e;

    int*   cnt        = (int*)d_ws;
    int*   row_ptr    = cnt + n;
    int*   cursor     = row_ptr + n;
    float* dinv       = (float*)(cursor + n);
    int*   part       = (int*)(dinv + n);
    int*   sorted_src = part + 512;
    float* Wt         = (float*)(sorted_src + e);
    unsigned short* y = (unsigned short*)(Wt + C * C);

    float* sout = (float*)d_out;

    int nb = (n + 255) / 256;
    int eb = (e + 255) / 256;

    k_init  <<<nb, 256, 0, stream>>>(W, Wt, cnt, n);
    k_hist  <<<eb, 256, 0, stream>>>(dst, cnt, e);
    k_scan_a<<<nb, 256, 0, stream>>>(cnt, part, n);
    k_scan_b<<<1, 512, 0, stream>>>(part, nb);
    k_scan_c<<<nb, 256, 0, stream>>>(cnt, part, row_ptr, cursor, dinv, n);
    k_place <<<eb, 256, 0, stream>>>(src, dst, cursor, sorted_src, e);
    k_ybf   <<<(n * 32 + 255) / 256, 256, 0, stream>>>(x, dinv, y, n);
    k_gather<<<(n + 3) / 4, 256, 0, stream>>>(y, x0, sorted_src, row_ptr, cnt, dinv, sout, n);
    k_out   <<<(n + 63) / 64, 256, 0, stream>>>(sout, Wt, b, sout, n);
}

// Round 7
// 169.470 us; speedup vs baseline: 1.2892x; 1.1519x over previous
//
#include <hip/hip_runtime.h>
#include <stdint.h>

#define C 128
#define ALPHA_F 0.1f
#define ONE_MINUS_ALPHA 0.9f
// beta = log(THETA/LAYER + 1) = log(1.25)
#define BETA_F 0.22314355131420976f
#define ONE_MINUS_BETA 0.7768564486857902f

typedef __attribute__((ext_vector_type(8))) short bf16x8;
typedef __attribute__((ext_vector_type(4))) float f32x4;

__device__ inline float bf2f(unsigned short u) {
    union { unsigned int i; float f; } c;
    c.i = ((unsigned int)u) << 16;
    return c.f;
}
__device__ inline unsigned short f2bf(float f) {
    union { float f; unsigned int i; } c;
    c.f = f;
    unsigned int r = (c.i + 0x7FFFu + ((c.i >> 16) & 1u)) >> 16;  // RNE
    return (unsigned short)r;
}

// ---------------- init: zero cnt + W -> bf16 (row-major, untransposed) -----
__global__ void k_init(const float* __restrict__ W, unsigned short* __restrict__ Wb,
                       int* __restrict__ cnt, int n) {
    int i = blockIdx.x * 256 + threadIdx.x;
    if (i < n) cnt[i] = 0;
    if (i < C * C) Wb[i] = f2bf(W[i]);
}

__global__ void k_hist(const int* __restrict__ dst, int* __restrict__ cnt, int e) {
    int i = blockIdx.x * blockDim.x + threadIdx.x;
    if (i < e) atomicAdd(&cnt[dst[i]], 1);
}

__global__ __launch_bounds__(256)
void k_scan_a(const int* __restrict__ cnt, int* __restrict__ part, int n) {
    __shared__ int s[256];
    int t = threadIdx.x;
    int i = blockIdx.x * 256 + t;
    s[t] = (i < n) ? cnt[i] : 0;
    __syncthreads();
    for (int off = 128; off > 0; off >>= 1) {
        if (t < off) s[t] += s[t + off];
        __syncthreads();
    }
    if (t == 0) part[blockIdx.x] = s[0];
}

__global__ __launch_bounds__(512)
void k_scan_b(int* __restrict__ part, int np) {
    __shared__ int a[512];
    __shared__ int b[512];
    int t = threadIdx.x;
    a[t] = (t < np) ? part[t] : 0;
    __syncthreads();
    int* cur = a;
    int* nxt = b;
    for (int off = 1; off < 512; off <<= 1) {
        nxt[t] = cur[t] + ((t >= off) ? cur[t - off] : 0);
        __syncthreads();
        int* tmp = cur; cur = nxt; nxt = tmp;
    }
    if (t < np) part[t] = (t > 0) ? cur[t - 1] : 0;  // exclusive
}

__global__ __launch_bounds__(256)
void k_scan_c(const int* __restrict__ cnt, const int* __restrict__ part,
              int* __restrict__ row_ptr, int* __restrict__ cursor,
              float* __restrict__ dinv, int n) {
    __shared__ int a[256];
    __shared__ int b[256];
    int t = threadIdx.x;
    int i = blockIdx.x * 256 + t;
    int v = (i < n) ? cnt[i] : 0;
    a[t] = v;
    __syncthreads();
    int* cur = a;
    int* nxt = b;
    for (int off = 1; off < 256; off <<= 1) {
        nxt[t] = cur[t] + ((t >= off) ? cur[t - off] : 0);
        __syncthreads();
        int* tmp = cur; cur = nxt; nxt = tmp;
    }
    if (i < n) {
        int rp = part[blockIdx.x] + cur[t] - v;
        row_ptr[i] = rp;
        cursor[i]  = rp;
        dinv[i]    = rsqrtf((float)(v + 1));  // deg includes self-loop
    }
}

__global__ void k_place(const int* __restrict__ src, const int* __restrict__ dst,
                        int* __restrict__ cursor, int* __restrict__ sorted_src, int e) {
    int i = blockIdx.x * blockDim.x + threadIdx.x;
    if (i < e) {
        int d = dst[i];
        int pos = atomicAdd(&cursor[d], 1);
        sorted_src[pos] = src[i];
    }
}

// y[i][:] = bf16(x[i][:] * dinv[i])  -- 25.6 MB, L2/L3-resident for the gather
__global__ void k_ybf(const float* __restrict__ x, const float* __restrict__ dinv,
                      unsigned short* __restrict__ y, int n) {
    int t = blockIdx.x * 256 + threadIdx.x;
    int total = n * 32;
    if (t < total) {
        int i = t >> 5;
        float dv = dinv[i];
        float4 v = ((const float4*)x)[t];
        ushort4 o;
        o.x = f2bf(v.x * dv);
        o.y = f2bf(v.y * dv);
        o.z = f2bf(v.z * dv);
        o.w = f2bf(v.w * dv);
        ((ushort4*)y)[t] = o;
    }
}

// ---------------- gather + alpha-blend -> sout ----------------
__global__ __launch_bounds__(256)
void k_gather(const unsigned short* __restrict__ y, const float* __restrict__ x0,
              const int* __restrict__ sorted_src, const int* __restrict__ row_ptr,
              const int* __restrict__ cnt, const float* __restrict__ dinv,
              float* __restrict__ sout, int n) {
    int lane = threadIdx.x & 63;
    int half = lane >> 5;
    int l32  = lane & 31;
    int idx  = blockIdx.x * 4 + (threadIdx.x >> 6);
    if (idx >= n) return;

    const ushort4* y4 = (const ushort4*)y;

    float dv  = dinv[idx];
    int start = row_ptr[idx];
    int len   = cnt[idx];
    float4 xv = ((const float4*)x0)[(size_t)idx * 32 + l32];

    int m = (len < 64) ? len : 64;
    int eidx = (lane < m) ? sorted_src[start + lane] : idx;  // pad = self (valid row)

    float4 acc = make_float4(0.f, 0.f, 0.f, 0.f);

    for (int j = half; j < m; j += 8) {   // 4 edges per half per batch
        bool b1 = (j + 2) < m;
        bool b2 = (j + 4) < m;
        bool b3 = (j + 6) < m;
        int i1 = b1 ? j + 2 : j;
        int i2 = b2 ? j + 4 : j;
        int i3 = b3 ? j + 6 : j;
        int s0 = __shfl(eidx, j, 64);
        int s1 = __shfl(eidx, i1, 64);
        int s2 = __shfl(eidx, i2, 64);
        int s3 = __shfl(eidx, i3, 64);
        ushort4 v0 = y4[(size_t)s0 * 32 + l32];
        ushort4 v1 = y4[(size_t)s1 * 32 + l32];
        ushort4 v2 = y4[(size_t)s2 * 32 + l32];
        ushort4 v3 = y4[(size_t)s3 * 32 + l32];
        float w1 = b1 ? 1.f : 0.f;
        float w2 = b2 ? 1.f : 0.f;
        float w3 = b3 ? 1.f : 0.f;
        acc.x += bf2f(v0.x) + w1 * bf2f(v1.x) + w2 * bf2f(v2.x) + w3 * bf2f(v3.x);
        acc.y += bf2f(v0.y) + w1 * bf2f(v1.y) + w2 * bf2f(v2.y) + w3 * bf2f(v3.y);
        acc.z += bf2f(v0.z) + w1 * bf2f(v1.z) + w2 * bf2f(v2.z) + w3 * bf2f(v3.z);
        acc.w += bf2f(v0.w) + w1 * bf2f(v1.w) + w2 * bf2f(v2.w) + w3 * bf2f(v3.w);
    }

    for (int j = 64 + half; j < len; j += 2) {  // rare: degree > 64
        int s0 = sorted_src[start + j];
        ushort4 v0 = y4[(size_t)s0 * 32 + l32];
        acc.x += bf2f(v0.x);
        acc.y += bf2f(v0.y);
        acc.z += bf2f(v0.z);
        acc.w += bf2f(v0.w);
    }

    if (half == 0) {  // self-loop term
        ushort4 vs = y4[(size_t)idx * 32 + l32];
        acc.x += bf2f(vs.x);
        acc.y += bf2f(vs.y);
        acc.z += bf2f(vs.z);
        acc.w += bf2f(vs.w);
    }

    acc.x += __shfl_xor(acc.x, 32, 64);
    acc.y += __shfl_xor(acc.y, 32, 64);
    acc.z += __shfl_xor(acc.z, 32, 64);
    acc.w += __shfl_xor(acc.w, 32, 64);

    if (half == 0) {
        float4 o;
        o.x = ONE_MINUS_ALPHA * (dv * acc.x) + ALPHA_F * xv.x;
        o.y = ONE_MINUS_ALPHA * (dv * acc.y) + ALPHA_F * xv.y;
        o.z = ONE_MINUS_ALPHA * (dv * acc.z) + ALPHA_F * xv.z;
        o.w = ONE_MINUS_ALPHA * (dv * acc.w) + ALPHA_F * xv.w;
        ((float4*)sout)[(size_t)idx * 32 + l32] = o;
    }
}

// ---------------- MFMA epilogue GEMM ----------------
// out = (1-beta)*s + beta*(s @ W^T + b).
// D = A*B: A = s[64 rows][K=128] bf16, B[k][j] = W[j][k] -> B-frag reads
// Wb[j][k] rows contiguously (B^T pattern). mfma_f32_16x16x32_bf16:
//   A: row=lane&15, k=8*(lane>>4)+i ; B: col(j)=lane&15, k=8*(lane>>4)+i
//   D: col=lane&15, row=4*(lane>>4)+reg   [guide m89/m91]
// LDS tiles swizzled on 16B granules: g ^= (row&7) -> <=2-way conflicts.
__global__ __launch_bounds__(256)
void k_out(const float* __restrict__ sin, const unsigned short* __restrict__ Wb,
           const float* __restrict__ bias, float* __restrict__ out, int n) {
    __shared__ unsigned short wlds[128 * 128];  // 32 KB, swizzled
    __shared__ unsigned short slds[64 * 128];   // 16 KB, swizzled

    int tid  = threadIdx.x;
    int row0 = blockIdx.x * 64;

    // stage Wb (2048 granules of 16B)
    const uint4* Wb16 = (const uint4*)Wb;
    for (int i = tid; i < 2048; i += 256) {
        int j = i >> 4;
        int g = i & 15;
        uint4 v = Wb16[i];
        *(uint4*)&wlds[j * 128 + (g ^ (j & 7)) * 8] = v;
    }
    // stage s tile -> bf16 (1024 granules)
    for (int i = tid; i < 1024; i += 256) {
        int r = i >> 4;
        int g = i & 15;
        int grow = row0 + r;
        union { unsigned short u[8]; uint4 v; } pk;
        if (grow < n) {
            const float* p = sin + (size_t)grow * C + g * 8;
            float4 aa = *(const float4*)p;
            float4 bb = *(const float4*)(p + 4);
            pk.u[0] = f2bf(aa.x); pk.u[1] = f2bf(aa.y);
            pk.u[2] = f2bf(aa.z); pk.u[3] = f2bf(aa.w);
            pk.u[4] = f2bf(bb.x); pk.u[5] = f2bf(bb.y);
            pk.u[6] = f2bf(bb.z); pk.u[7] = f2bf(bb.w);
        } else {
            pk.v = make_uint4(0, 0, 0, 0);
        }
        *(uint4*)&slds[r * 128 + (g ^ (r & 7)) * 8] = pk.v;
    }
    __syncthreads();

    int w    = tid >> 6;
    int lane = tid & 63;
    int l16  = lane & 15;
    int h    = lane >> 4;
    int arow = w * 16 + l16;

    f32x4 acc[8];
    #pragma unroll
    for (int t = 0; t < 8; ++t) acc[t] = (f32x4){0.f, 0.f, 0.f, 0.f};

    #pragma unroll
    for (int k0 = 0; k0 < 128; k0 += 32) {
        int ga = ((k0 >> 3) + h) ^ (arow & 7);
        bf16x8 a = *(const bf16x8*)&slds[arow * 128 + ga * 8];
        #pragma unroll
        for (int t = 0; t < 8; ++t) {
            int brow = t * 16 + l16;
            int gb = ((k0 >> 3) + h) ^ (brow & 7);
            bf16x8 b = *(const bf16x8*)&wlds[brow * 128 + gb * 8];
            acc[t] = __builtin_amdgcn_mfma_f32_16x16x32_bf16(a, b, acc[t], 0, 0, 0);
        }
    }

    #pragma unroll
    for (int t = 0; t < 8; ++t) {
        int j  = t * 16 + l16;
        float bj = bias[j];
        #pragma unroll
        for (int e2 = 0; e2 < 4; ++e2) {
            int grow = row0 + w * 16 + h * 4 + e2;
            if (grow < n) {
                float sv = sin[(size_t)grow * C + j];
                out[(size_t)grow * C + j] =
                    ONE_MINUS_BETA * sv + BETA_F * (acc[t][e2] + bj);
            }
        }
    }
}

extern "C" void kernel_launch(void* const* d_in, const int* in_sizes, int n_in,
                              void* d_out, int out_size, void* d_ws, size_t ws_size,
                              hipStream_t stream) {
    const float* x   = (const float*)d_in[0];
    const float* x0  = (const float*)d_in[1];
    const float* W   = (const float*)d_in[2];
    const float* b   = (const float*)d_in[3];
    const int*   ei  = (const int*)d_in[4];

    int n = in_sizes[0] / C;
    int e = in_sizes[4] / 2;
    const int* src = ei;
    const int* dst = ei + e;

    int*   cnt        = (int*)d_ws;
    int*   row_ptr    = cnt + n;
    int*   cursor     = row_ptr + n;
    float* dinv       = (float*)(cursor + n);
    int*   part       = (int*)(dinv + n);
    int*   sorted_src = part + 512;
    unsigned short* Wb = (unsigned short*)(sorted_src + e);
    unsigned short* y  = Wb + C * C;

    float* sout = (float*)d_out;

    int nb = (n + 255) / 256;
    int eb = (e + 255) / 256;

    k_init  <<<nb, 256, 0, stream>>>(W, Wb, cnt, n);
    k_hist  <<<eb, 256, 0, stream>>>(dst, cnt, e);
    k_scan_a<<<nb, 256, 0, stream>>>(cnt, part, n);
    k_scan_b<<<1, 512, 0, stream>>>(part, nb);
    k_scan_c<<<nb, 256, 0, stream>>>(cnt, part, row_ptr, cursor, dinv, n);
    k_place <<<eb, 256, 0, stream>>>(src, dst, cursor, sorted_src, e);
    k_ybf   <<<(n * 32 + 255) / 256, 256, 0, stream>>>(x, dinv, y, n);
    k_gather<<<(n + 3) / 4, 256, 0, stream>>>(y, x0, sorted_src, row_ptr, cnt, dinv, sout, n);
    k_out   <<<(n + 63) / 64, 256, 0, stream>>>(sout, Wb, b, sout, n);
}

// Round 8
// 149.246 us; speedup vs baseline: 1.4639x; 1.1355x over previous
//
#include <hip/hip_runtime.h>
#include <stdint.h>

#define C 128
#define ALPHA_F 0.1f
#define ONE_MINUS_ALPHA 0.9f
// beta = log(THETA/LAYER + 1) = log(1.25)
#define BETA_F 0.22314355131420976f
#define ONE_MINUS_BETA 0.7768564486857902f

typedef __attribute__((ext_vector_type(8))) short bf16x8;
typedef __attribute__((ext_vector_type(4))) float f32x4;

__device__ inline float bf2f(unsigned short u) {
    union { unsigned int i; float f; } c;
    c.i = ((unsigned int)u) << 16;
    return c.f;
}
__device__ inline unsigned short f2bf(float f) {
    union { float f; unsigned int i; } c;
    c.f = f;
    unsigned int r = (c.i + 0x7FFFu + ((c.i >> 16) & 1u)) >> 16;  // RNE
    return (unsigned short)r;
}

// ---- init: zero cnt + V = (1-beta)*I + beta*W^T, stored Vb[j][k] bf16 ----
__global__ void k_init(const float* __restrict__ W, unsigned short* __restrict__ Vb,
                       int* __restrict__ cnt, int n) {
    int i = blockIdx.x * 256 + threadIdx.x;
    if (i < n) cnt[i] = 0;
    if (i < C * C) {
        int j = i >> 7;   // W row = output index
        int c = i & 127;  // k index
        float v = BETA_F * W[i] + ((j == c) ? ONE_MINUS_BETA : 0.f);
        Vb[i] = f2bf(v);
    }
}

__global__ void k_hist(const int* __restrict__ dst, int* __restrict__ cnt, int e) {
    int i = blockIdx.x * blockDim.x + threadIdx.x;
    if (i < e) atomicAdd(&cnt[dst[i]], 1);
}

__global__ __launch_bounds__(256)
void k_scan_a(const int* __restrict__ cnt, int* __restrict__ part, int n) {
    __shared__ int s[256];
    int t = threadIdx.x;
    int i = blockIdx.x * 256 + t;
    s[t] = (i < n) ? cnt[i] : 0;
    __syncthreads();
    for (int off = 128; off > 0; off >>= 1) {
        if (t < off) s[t] += s[t + off];
        __syncthreads();
    }
    if (t == 0) part[blockIdx.x] = s[0];
}

__global__ __launch_bounds__(512)
void k_scan_b(int* __restrict__ part, int np) {
    __shared__ int a[512];
    __shared__ int b[512];
    int t = threadIdx.x;
    a[t] = (t < np) ? part[t] : 0;
    __syncthreads();
    int* cur = a;
    int* nxt = b;
    for (int off = 1; off < 512; off <<= 1) {
        nxt[t] = cur[t] + ((t >= off) ? cur[t - off] : 0);
        __syncthreads();
        int* tmp = cur; cur = nxt; nxt = tmp;
    }
    if (t < np) part[t] = (t > 0) ? cur[t - 1] : 0;  // exclusive
}

__global__ __launch_bounds__(256)
void k_scan_c(const int* __restrict__ cnt, const int* __restrict__ part,
              int* __restrict__ row_ptr, int* __restrict__ cursor,
              float* __restrict__ dinv, int n) {
    __shared__ int a[256];
    __shared__ int b[256];
    int t = threadIdx.x;
    int i = blockIdx.x * 256 + t;
    int v = (i < n) ? cnt[i] : 0;
    a[t] = v;
    __syncthreads();
    int* cur = a;
    int* nxt = b;
    for (int off = 1; off < 256; off <<= 1) {
        nxt[t] = cur[t] + ((t >= off) ? cur[t - off] : 0);
        __syncthreads();
        int* tmp = cur; cur = nxt; nxt = tmp;
    }
    if (i < n) {
        int rp = part[blockIdx.x] + cur[t] - v;
        row_ptr[i] = rp;
        cursor[i]  = rp;
        dinv[i]    = rsqrtf((float)(v + 1));  // deg includes self-loop
    }
}

__global__ void k_place(const int* __restrict__ src, const int* __restrict__ dst,
                        int* __restrict__ cursor, int* __restrict__ sorted_src, int e) {
    int i = blockIdx.x * blockDim.x + threadIdx.x;
    if (i < e) {
        int d = dst[i];
        int pos = atomicAdd(&cursor[d], 1);
        sorted_src[pos] = src[i];
    }
}

// y[i][:] = bf16(x[i][:] * dinv[i])
__global__ void k_ybf(const float* __restrict__ x, const float* __restrict__ dinv,
                      unsigned short* __restrict__ y, int n) {
    int t = blockIdx.x * 256 + threadIdx.x;
    int total = n * 32;
    if (t < total) {
        int i = t >> 5;
        float dv = dinv[i];
        float4 v = ((const float4*)x)[t];
        ushort4 o;
        o.x = f2bf(v.x * dv);
        o.y = f2bf(v.y * dv);
        o.z = f2bf(v.z * dv);
        o.w = f2bf(v.w * dv);
        ((ushort4*)y)[t] = o;
    }
}

// ---------------- gather + alpha-blend -> s (bf16 ws or fp32 d_out) --------
// 2 nodes/wave: each half-wave (32 lanes = full 256B row) owns a node.
// Edge list preloaded (<=32 per node, one index/lane), broadcast via shfl.
// 8 weight-clamped y-row loads issued up-front (covers deg<=8), then 4-wide
// batches to 32, uniform tail beyond.
__global__ __launch_bounds__(256)
void k_gather(const unsigned short* __restrict__ y, const float* __restrict__ x0,
              const int* __restrict__ sorted_src, const int* __restrict__ row_ptr,
              const int* __restrict__ cnt, const float* __restrict__ dinv,
              float* __restrict__ soutf, unsigned short* __restrict__ soutb,
              int mode, int n) {
    int tid  = threadIdx.x;
    int l32  = tid & 31;
    int base = tid & 32;                 // this half's lane base within the wave
    int node = blockIdx.x * 8 + (tid >> 5);
    if (node >= n) return;

    const ushort4* y4 = (const ushort4*)y;

    float dv  = dinv[node];
    int start = row_ptr[node];
    int len   = cnt[node];
    float4 xv = ((const float4*)x0)[(size_t)node * 32 + l32];

    int m = (len < 32) ? len : 32;
    int eidx = (l32 < m) ? sorted_src[start + l32] : node;  // pad = self (valid row)

    // 8 clamped slots, all loads independent + self row
    bool b0 = 0 < m, b1 = 1 < m, b2 = 2 < m, b3 = 3 < m;
    bool b4 = 4 < m, b5 = 5 < m, b6 = 6 < m, b7 = 7 < m;
    int s0 = __shfl(eidx, base + 0, 64);
    int s1 = __shfl(eidx, base + (b1 ? 1 : 0), 64);
    int s2 = __shfl(eidx, base + (b2 ? 2 : 0), 64);
    int s3 = __shfl(eidx, base + (b3 ? 3 : 0), 64);
    int s4 = __shfl(eidx, base + (b4 ? 4 : 0), 64);
    int s5 = __shfl(eidx, base + (b5 ? 5 : 0), 64);
    int s6 = __shfl(eidx, base + (b6 ? 6 : 0), 64);
    int s7 = __shfl(eidx, base + (b7 ? 7 : 0), 64);
    ushort4 v0 = y4[(size_t)s0 * 32 + l32];
    ushort4 v1 = y4[(size_t)s1 * 32 + l32];
    ushort4 v2 = y4[(size_t)s2 * 32 + l32];
    ushort4 v3 = y4[(size_t)s3 * 32 + l32];
    ushort4 v4 = y4[(size_t)s4 * 32 + l32];
    ushort4 v5 = y4[(size_t)s5 * 32 + l32];
    ushort4 v6 = y4[(size_t)s6 * 32 + l32];
    ushort4 v7 = y4[(size_t)s7 * 32 + l32];
    ushort4 vs = y4[(size_t)node * 32 + l32];   // self-loop row

    float w0 = b0 ? 1.f : 0.f, w1 = b1 ? 1.f : 0.f, w2 = b2 ? 1.f : 0.f, w3 = b3 ? 1.f : 0.f;
    float w4 = b4 ? 1.f : 0.f, w5 = b5 ? 1.f : 0.f, w6 = b6 ? 1.f : 0.f, w7 = b7 ? 1.f : 0.f;

    float4 acc;
    acc.x = bf2f(vs.x) + w0 * bf2f(v0.x) + w1 * bf2f(v1.x) + w2 * bf2f(v2.x) + w3 * bf2f(v3.x)
                       + w4 * bf2f(v4.x) + w5 * bf2f(v5.x) + w6 * bf2f(v6.x) + w7 * bf2f(v7.x);
    acc.y = bf2f(vs.y) + w0 * bf2f(v0.y) + w1 * bf2f(v1.y) + w2 * bf2f(v2.y) + w3 * bf2f(v3.y)
                       + w4 * bf2f(v4.y) + w5 * bf2f(v5.y) + w6 * bf2f(v6.y) + w7 * bf2f(v7.y);
    acc.z = bf2f(vs.z) + w0 * bf2f(v0.z) + w1 * bf2f(v1.z) + w2 * bf2f(v2.z) + w3 * bf2f(v3.z)
                       + w4 * bf2f(v4.z) + w5 * bf2f(v5.z) + w6 * bf2f(v6.z) + w7 * bf2f(v7.z);
    acc.w = bf2f(vs.w) + w0 * bf2f(v0.w) + w1 * bf2f(v1.w) + w2 * bf2f(v2.w) + w3 * bf2f(v3.w)
                       + w4 * bf2f(v4.w) + w5 * bf2f(v5.w) + w6 * bf2f(v6.w) + w7 * bf2f(v7.w);

    for (int j = 8; j < m; j += 4) {     // 9..32 incident edges
        bool c1 = (j + 1) < m, c2 = (j + 2) < m, c3 = (j + 3) < m;
        int t0 = __shfl(eidx, base + j, 64);
        int t1 = __shfl(eidx, base + (c1 ? j + 1 : j), 64);
        int t2 = __shfl(eidx, base + (c2 ? j + 2 : j), 64);
        int t3 = __shfl(eidx, base + (c3 ? j + 3 : j), 64);
        ushort4 u0 = y4[(size_t)t0 * 32 + l32];
        ushort4 u1 = y4[(size_t)t1 * 32 + l32];
        ushort4 u2 = y4[(size_t)t2 * 32 + l32];
        ushort4 u3 = y4[(size_t)t3 * 32 + l32];
        float q1 = c1 ? 1.f : 0.f, q2 = c2 ? 1.f : 0.f, q3 = c3 ? 1.f : 0.f;
        acc.x += bf2f(u0.x) + q1 * bf2f(u1.x) + q2 * bf2f(u2.x) + q3 * bf2f(u3.x);
        acc.y += bf2f(u0.y) + q1 * bf2f(u1.y) + q2 * bf2f(u2.y) + q3 * bf2f(u3.y);
        acc.z += bf2f(u0.z) + q1 * bf2f(u1.z) + q2 * bf2f(u2.z) + q3 * bf2f(u3.z);
        acc.w += bf2f(u0.w) + q1 * bf2f(u1.w) + q2 * bf2f(u2.w) + q3 * bf2f(u3.w);
    }

    for (int j = 32; j < len; ++j) {     // rare: degree > 32 (uniform broadcast)
        int t0 = sorted_src[start + j];
        ushort4 u0 = y4[(size_t)t0 * 32 + l32];
        acc.x += bf2f(u0.x);
        acc.y += bf2f(u0.y);
        acc.z += bf2f(u0.z);
        acc.w += bf2f(u0.w);
    }

    float4 s;
    s.x = ONE_MINUS_ALPHA * (dv * acc.x) + ALPHA_F * xv.x;
    s.y = ONE_MINUS_ALPHA * (dv * acc.y) + ALPHA_F * xv.y;
    s.z = ONE_MINUS_ALPHA * (dv * acc.z) + ALPHA_F * xv.z;
    s.w = ONE_MINUS_ALPHA * (dv * acc.w) + ALPHA_F * xv.w;

    if (mode) {
        ushort4 o;
        o.x = f2bf(s.x); o.y = f2bf(s.y); o.z = f2bf(s.z); o.w = f2bf(s.w);
        ((ushort4*)soutb)[(size_t)node * 32 + l32] = o;
    } else {
        ((float4*)soutf)[(size_t)node * 32 + l32] = s;
    }
}

// ---------------- MFMA GEMM: out = s @ V + beta*b ----------------
// V already folds the (1-beta)*s blend. A = s (bf16), B[k][j] = V read via
// Vb[j][k] rows (B^T pattern). mfma_f32_16x16x32_bf16 layouts per m89/m91.
// LDS 16B-granule XOR swizzle (g ^= row&7) -> <=2-way conflicts.
__global__ __launch_bounds__(256)
void k_out(const float* __restrict__ sinf, const unsigned short* __restrict__ sinb,
           const unsigned short* __restrict__ Vb, const float* __restrict__ bias,
           float* __restrict__ out, int mode, int n) {
    __shared__ unsigned short wlds[128 * 128];  // 32 KB
    __shared__ unsigned short slds[64 * 128];   // 16 KB

    int tid  = threadIdx.x;
    int row0 = blockIdx.x * 64;

    const uint4* Vb16 = (const uint4*)Vb;
    for (int i = tid; i < 2048; i += 256) {
        int j = i >> 4;
        int g = i & 15;
        uint4 v = Vb16[i];
        *(uint4*)&wlds[j * 128 + (g ^ (j & 7)) * 8] = v;
    }

    if (mode) {
        const uint4* sb16 = (const uint4*)sinb;
        for (int i = tid; i < 1024; i += 256) {
            int r = i >> 4;
            int g = i & 15;
            int grow = row0 + r;
            uint4 v = make_uint4(0, 0, 0, 0);
            if (grow < n) v = sb16[(size_t)grow * 16 + g];
            *(uint4*)&slds[r * 128 + (g ^ (r & 7)) * 8] = v;
        }
    } else {
        for (int i = tid; i < 1024; i += 256) {
            int r = i >> 4;
            int g = i & 15;
            int grow = row0 + r;
            union { unsigned short u[8]; uint4 v; } pk;
            if (grow < n) {
                const float* p = sinf + (size_t)grow * C + g * 8;
                float4 aa = *(const float4*)p;
                float4 bb = *(const float4*)(p + 4);
                pk.u[0] = f2bf(aa.x); pk.u[1] = f2bf(aa.y);
                pk.u[2] = f2bf(aa.z); pk.u[3] = f2bf(aa.w);
                pk.u[4] = f2bf(bb.x); pk.u[5] = f2bf(bb.y);
                pk.u[6] = f2bf(bb.z); pk.u[7] = f2bf(bb.w);
            } else {
                pk.v = make_uint4(0, 0, 0, 0);
            }
            *(uint4*)&slds[r * 128 + (g ^ (r & 7)) * 8] = pk.v;
        }
    }
    __syncthreads();

    int w    = tid >> 6;
    int lane = tid & 63;
    int l16  = lane & 15;
    int h    = lane >> 4;
    int arow = w * 16 + l16;

    f32x4 acc[8];
    #pragma unroll
    for (int t = 0; t < 8; ++t) acc[t] = (f32x4){0.f, 0.f, 0.f, 0.f};

    #pragma unroll
    for (int k0 = 0; k0 < 128; k0 += 32) {
        int ga = ((k0 >> 3) + h) ^ (arow & 7);
        bf16x8 a = *(const bf16x8*)&slds[arow * 128 + ga * 8];
        #pragma unroll
        for (int t = 0; t < 8; ++t) {
            int brow = t * 16 + l16;
            int gb = ((k0 >> 3) + h) ^ (brow & 7);
            bf16x8 b = *(const bf16x8*)&wlds[brow * 128 + gb * 8];
            acc[t] = __builtin_amdgcn_mfma_f32_16x16x32_bf16(a, b, acc[t], 0, 0, 0);
        }
    }

    #pragma unroll
    for (int t = 0; t < 8; ++t) {
        int j  = t * 16 + l16;
        float bj = BETA_F * bias[j];
        #pragma unroll
        for (int e2 = 0; e2 < 4; ++e2) {
            int grow = row0 + w * 16 + h * 4 + e2;
            if (grow < n) {
                out[(size_t)grow * C + j] = acc[t][e2] + bj;
            }
        }
    }
}

extern "C" void kernel_launch(void* const* d_in, const int* in_sizes, int n_in,
                              void* d_out, int out_size, void* d_ws, size_t ws_size,
                              hipStream_t stream) {
    const float* x   = (const float*)d_in[0];
    const float* x0  = (const float*)d_in[1];
    const float* W   = (const float*)d_in[2];
    const float* b   = (const float*)d_in[3];
    const int*   ei  = (const int*)d_in[4];

    int n = in_sizes[0] / C;
    int e = in_sizes[4] / 2;
    const int* src = ei;
    const int* dst = ei + e;

    int*   cnt        = (int*)d_ws;
    int*   row_ptr    = cnt + n;
    int*   cursor     = row_ptr + n;
    float* dinv       = (float*)(cursor + n);
    int*   part       = (int*)(dinv + n);
    int*   sorted_src = part + 512;
    unsigned short* Vb   = (unsigned short*)(sorted_src + e);
    unsigned short* y    = Vb + C * C;
    unsigned short* sb16 = y + (size_t)n * C;

    size_t need = (size_t)((char*)(sb16 + (size_t)n * C) - (char*)d_ws);
    int mode = (ws_size >= need) ? 1 : 0;

    float* sout = (float*)d_out;

    int nb = (n + 255) / 256;
    int eb = (e + 255) / 256;

    k_init  <<<nb, 256, 0, stream>>>(W, Vb, cnt, n);
    k_hist  <<<eb, 256, 0, stream>>>(dst, cnt, e);
    k_scan_a<<<nb, 256, 0, stream>>>(cnt, part, n);
    k_scan_b<<<1, 512, 0, stream>>>(part, nb);
    k_scan_c<<<nb, 256, 0, stream>>>(cnt, part, row_ptr, cursor, dinv, n);
    k_place <<<eb, 256, 0, stream>>>(src, dst, cursor, sorted_src, e);
    k_ybf   <<<(n * 32 + 255) / 256, 256, 0, stream>>>(x, dinv, y, n);
    k_gather<<<(n + 7) / 8, 256, 0, stream>>>(y, x0, sorted_src, row_ptr, cnt, dinv,
                                              sout, sb16, mode, n);
    k_out   <<<(n + 63) / 64, 256, 0, stream>>>(sout, sb16, Vb, b, sout, mode, n);
}

// Round 10
// 144.901 us; speedup vs baseline: 1.5078x; 1.0300x over previous
//
#include <hip/hip_runtime.h>
#include <stdint.h>

#define C 128
#define ALPHA_F 0.1f
#define ONE_MINUS_ALPHA 0.9f
// beta = log(THETA/LAYER + 1) = log(1.25)
#define BETA_F 0.22314355131420976f
#define ONE_MINUS_BETA 0.7768564486857902f

typedef __attribute__((ext_vector_type(8))) short bf16x8;
typedef __attribute__((ext_vector_type(4))) float f32x4;

__device__ inline float bf2f(unsigned short u) {
    union { unsigned int i; float f; } c;
    c.i = ((unsigned int)u) << 16;
    return c.f;
}
__device__ inline unsigned short f2bf(float f) {
    union { float f; unsigned int i; } c;
    c.f = f;
    unsigned int r = (c.i + 0x7FFFu + ((c.i >> 16) & 1u)) >> 16;  // RNE
    return (unsigned short)r;
}

// ---- init: zero cnt + V = (1-beta)*I + beta*W^T, stored Vb[j][k] bf16 ----
__global__ void k_init(const float* __restrict__ W, unsigned short* __restrict__ Vb,
                       int* __restrict__ cnt, int n) {
    int i = blockIdx.x * 256 + threadIdx.x;
    if (i < n) cnt[i] = 0;
    if (i < C * C) {
        int j = i >> 7;   // W row = output index
        int c = i & 127;  // k index
        float v = BETA_F * W[i] + ((j == c) ? ONE_MINUS_BETA : 0.f);
        Vb[i] = f2bf(v);
    }
}

__global__ void k_hist(const int* __restrict__ dst, int* __restrict__ cnt, int e) {
    int i = blockIdx.x * blockDim.x + threadIdx.x;
    if (i < e) atomicAdd(&cnt[dst[i]], 1);
}

__global__ __launch_bounds__(256)
void k_scan_a(const int* __restrict__ cnt, int* __restrict__ part, int n) {
    __shared__ int s[256];
    int t = threadIdx.x;
    int i = blockIdx.x * 256 + t;
    s[t] = (i < n) ? cnt[i] : 0;
    __syncthreads();
    for (int off = 128; off > 0; off >>= 1) {
        if (t < off) s[t] += s[t + off];
        __syncthreads();
    }
    if (t == 0) part[blockIdx.x] = s[0];
}

// merged scan_b + scan_c: each block reduces part[0..bid-1] itself, then does
// the per-element exclusive scan; emits meta{start,len,dinv}, cursor, dinv.
__global__ __launch_bounds__(256)
void k_scan_bc(const int* __restrict__ cnt, const int* __restrict__ part,
               int4* __restrict__ meta, int* __restrict__ cursor,
               float* __restrict__ dinv, int n) {
    __shared__ int a[256];
    __shared__ int b[256];
    int t   = threadIdx.x;
    int bid = blockIdx.x;

    // block offset = sum part[0..bid-1]
    int local = 0;
    for (int k = t; k < bid; k += 256) local += part[k];
    a[t] = local;
    __syncthreads();
    for (int off = 128; off > 0; off >>= 1) {
        if (t < off) a[t] += a[t + off];
        __syncthreads();
    }
    int blockoff = a[0];
    __syncthreads();

    int i = bid * 256 + t;
    int v = (i < n) ? cnt[i] : 0;
    a[t] = v;
    __syncthreads();
    int* cur = a;
    int* nxt = b;
    for (int off = 1; off < 256; off <<= 1) {
        nxt[t] = cur[t] + ((t >= off) ? cur[t - off] : 0);
        __syncthreads();
        int* tmp = cur; cur = nxt; nxt = tmp;
    }
    if (i < n) {
        int rp = blockoff + cur[t] - v;        // exclusive prefix
        float dv = rsqrtf((float)(v + 1));     // deg includes self-loop
        meta[i]   = make_int4(rp, v, __float_as_int(dv), 0);
        cursor[i] = rp;
        dinv[i]   = dv;
    }
}

// merged place + ybf: blocks [0,eb) place edges; blocks [eb,..) build y.
__global__ void k_pl_ybf(const int* __restrict__ src, const int* __restrict__ dst,
                         int* __restrict__ cursor, int* __restrict__ sorted_src, int e,
                         const float* __restrict__ x, const float* __restrict__ dinv,
                         unsigned short* __restrict__ y, int n, int eb) {
    int bid = blockIdx.x;
    if (bid < eb) {
        int i = bid * 256 + threadIdx.x;
        if (i < e) {
            int d = dst[i];
            int pos = atomicAdd(&cursor[d], 1);
            sorted_src[pos] = src[i];
        }
    } else {
        int t = (bid - eb) * 256 + threadIdx.x;
        int total = n * 32;
        if (t < total) {
            int i = t >> 5;
            float dv = dinv[i];
            float4 v = ((const float4*)x)[t];
            ushort4 o;
            o.x = f2bf(v.x * dv);
            o.y = f2bf(v.y * dv);
            o.z = f2bf(v.z * dv);
            o.w = f2bf(v.w * dv);
            ((ushort4*)y)[t] = o;
        }
    }
}

// ---------------- gather -> p = 0.9*dinv*(sum y) (bf16 ws or fp32 d_out) ----
// 2 nodes/wave: each half-wave (32 lanes = full 256B row) owns a node.
// meta int4 = one load for {start,len,dinv}. 8 weight-clamped y-row loads
// up-front (covers deg<=8), 4-wide batches to 32, uniform tail beyond.
// x0 blend moved to k_out (keeps this kernel's byte count minimal).
__global__ __launch_bounds__(256)
void k_gather(const unsigned short* __restrict__ y, const int* __restrict__ sorted_src,
              const int4* __restrict__ meta,
              float* __restrict__ poutf, unsigned short* __restrict__ poutb,
              int mode, int n) {
    int tid  = threadIdx.x;
    int l32  = tid & 31;
    int base = tid & 32;                 // this half's lane base within the wave
    int node = blockIdx.x * 8 + (tid >> 5);
    if (node >= n) return;

    const ushort4* y4 = (const ushort4*)y;

    int4 md  = meta[node];
    int start = md.x;
    int len   = md.y;
    float dv  = __int_as_float(md.z);

    int m = (len < 32) ? len : 32;
    int eidx = (l32 < m) ? sorted_src[start + l32] : node;  // pad = self (valid row)

    bool b1 = 1 < m, b2 = 2 < m, b3 = 3 < m;
    bool b4 = 4 < m, b5 = 5 < m, b6 = 6 < m, b7 = 7 < m;
    int s0 = __shfl(eidx, base + 0, 64);
    int s1 = __shfl(eidx, base + (b1 ? 1 : 0), 64);
    int s2 = __shfl(eidx, base + (b2 ? 2 : 0), 64);
    int s3 = __shfl(eidx, base + (b3 ? 3 : 0), 64);
    int s4 = __shfl(eidx, base + (b4 ? 4 : 0), 64);
    int s5 = __shfl(eidx, base + (b5 ? 5 : 0), 64);
    int s6 = __shfl(eidx, base + (b6 ? 6 : 0), 64);
    int s7 = __shfl(eidx, base + (b7 ? 7 : 0), 64);
    ushort4 v0 = y4[(size_t)s0 * 32 + l32];
    ushort4 v1 = y4[(size_t)s1 * 32 + l32];
    ushort4 v2 = y4[(size_t)s2 * 32 + l32];
    ushort4 v3 = y4[(size_t)s3 * 32 + l32];
    ushort4 v4 = y4[(size_t)s4 * 32 + l32];
    ushort4 v5 = y4[(size_t)s5 * 32 + l32];
    ushort4 v6 = y4[(size_t)s6 * 32 + l32];
    ushort4 v7 = y4[(size_t)s7 * 32 + l32];
    ushort4 vs = y4[(size_t)node * 32 + l32];   // self-loop row

    float w0 = (0 < m) ? 1.f : 0.f, w1 = b1 ? 1.f : 0.f, w2 = b2 ? 1.f : 0.f, w3 = b3 ? 1.f : 0.f;
    float w4 = b4 ? 1.f : 0.f, w5 = b5 ? 1.f : 0.f, w6 = b6 ? 1.f : 0.f, w7 = b7 ? 1.f : 0.f;

    float4 acc;
    acc.x = bf2f(vs.x) + w0 * bf2f(v0.x) + w1 * bf2f(v1.x) + w2 * bf2f(v2.x) + w3 * bf2f(v3.x)
                       + w4 * bf2f(v4.x) + w5 * bf2f(v5.x) + w6 * bf2f(v6.x) + w7 * bf2f(v7.x);
    acc.y = bf2f(vs.y) + w0 * bf2f(v0.y) + w1 * bf2f(v1.y) + w2 * bf2f(v2.y) + w3 * bf2f(v3.y)
                       + w4 * bf2f(v4.y) + w5 * bf2f(v5.y) + w6 * bf2f(v6.y) + w7 * bf2f(v7.y);
    acc.z = bf2f(vs.z) + w0 * bf2f(v0.z) + w1 * bf2f(v1.z) + w2 * bf2f(v2.z) + w3 * bf2f(v3.z)
                       + w4 * bf2f(v4.z) + w5 * bf2f(v5.z) + w6 * bf2f(v6.z) + w7 * bf2f(v7.z);
    acc.w = bf2f(vs.w) + w0 * bf2f(v0.w) + w1 * bf2f(v1.w) + w2 * bf2f(v2.w) + w3 * bf2f(v3.w)
                       + w4 * bf2f(v4.w) + w5 * bf2f(v5.w) + w6 * bf2f(v6.w) + w7 * bf2f(v7.w);

    for (int j = 8; j < m; j += 4) {     // 9..32 incident edges
        bool c1 = (j + 1) < m, c2 = (j + 2) < m, c3 = (j + 3) < m;
        int t0 = __shfl(eidx, base + j, 64);
        int t1 = __shfl(eidx, base + (c1 ? j + 1 : j), 64);
        int t2 = __shfl(eidx, base + (c2 ? j + 2 : j), 64);
        int t3 = __shfl(eidx, base + (c3 ? j + 3 : j), 64);
        ushort4 u0 = y4[(size_t)t0 * 32 + l32];
        ushort4 u1 = y4[(size_t)t1 * 32 + l32];
        ushort4 u2 = y4[(size_t)t2 * 32 + l32];
        ushort4 u3 = y4[(size_t)t3 * 32 + l32];
        float q1 = c1 ? 1.f : 0.f, q2 = c2 ? 1.f : 0.f, q3 = c3 ? 1.f : 0.f;
        acc.x += bf2f(u0.x) + q1 * bf2f(u1.x) + q2 * bf2f(u2.x) + q3 * bf2f(u3.x);
        acc.y += bf2f(u0.y) + q1 * bf2f(u1.y) + q2 * bf2f(u2.y) + q3 * bf2f(u3.y);
        acc.z += bf2f(u0.z) + q1 * bf2f(u1.z) + q2 * bf2f(u2.z) + q3 * bf2f(u3.z);
        acc.w += bf2f(u0.w) + q1 * bf2f(u1.w) + q2 * bf2f(u2.w) + q3 * bf2f(u3.w);
    }

    for (int j = 32; j < len; ++j) {     // rare: degree > 32 (uniform broadcast)
        int t0 = sorted_src[start + j];
        ushort4 u0 = y4[(size_t)t0 * 32 + l32];
        acc.x += bf2f(u0.x);
        acc.y += bf2f(u0.y);
        acc.z += bf2f(u0.z);
        acc.w += bf2f(u0.w);
    }

    float k = ONE_MINUS_ALPHA * dv;
    if (mode) {
        unsigned long long pk =
            (unsigned long long)f2bf(k * acc.x)
          | ((unsigned long long)f2bf(k * acc.y) << 16)
          | ((unsigned long long)f2bf(k * acc.z) << 32)
          | ((unsigned long long)f2bf(k * acc.w) << 48);
        __builtin_nontemporal_store(
            pk, (unsigned long long*)(poutb + (size_t)node * C + l32 * 4));
    } else {
        float4 o = make_float4(k * acc.x, k * acc.y, k * acc.z, k * acc.w);
        ((float4*)poutf)[(size_t)node * 32 + l32] = o;
    }
}

// ---------------- MFMA GEMM: out = (p + 0.1*x0) @ V + beta*b ----------------
// V folds the (1-beta)*s blend; staging folds the alpha blend (s = p + 0.1*x0).
// A = s (bf16), B[k][j] = V via Vb[j][k] rows (B^T pattern). Layouts per
// m89/m91. LDS 16B-granule XOR swizzle (g ^= row&7) -> <=2-way conflicts.
__global__ __launch_bounds__(256)
void k_out(const float* __restrict__ pinf, const unsigned short* __restrict__ pinb,
           const float* __restrict__ x0,
           const unsigned short* __restrict__ Vb, const float* __restrict__ bias,
           float* __restrict__ out, int mode, int n) {
    __shared__ unsigned short wlds[128 * 128];  // 32 KB
    __shared__ unsigned short slds[64 * 128];   // 16 KB

    int tid  = threadIdx.x;
    int row0 = blockIdx.x * 64;

    const uint4* Vb16 = (const uint4*)Vb;
    for (int i = tid; i < 2048; i += 256) {
        int j = i >> 4;
        int g = i & 15;
        uint4 v = Vb16[i];
        *(uint4*)&wlds[j * 128 + (g ^ (j & 7)) * 8] = v;
    }

    for (int i = tid; i < 1024; i += 256) {
        int r = i >> 4;
        int g = i & 15;
        int grow = row0 + r;
        union { unsigned short u[8]; uint4 v; } pk;
        if (grow < n) {
            const float* xp = x0 + (size_t)grow * C + g * 8;
            float4 xa = *(const float4*)xp;
            float4 xb = *(const float4*)(xp + 4);
            if (mode) {
                uint4 pv = ((const uint4*)pinb)[(size_t)grow * 16 + g];
                unsigned short* pu = (unsigned short*)&pv;
                pk.u[0] = f2bf(bf2f(pu[0]) + ALPHA_F * xa.x);
                pk.u[1] = f2bf(bf2f(pu[1]) + ALPHA_F * xa.y);
                pk.u[2] = f2bf(bf2f(pu[2]) + ALPHA_F * xa.z);
                pk.u[3] = f2bf(bf2f(pu[3]) + ALPHA_F * xa.w);
                pk.u[4] = f2bf(bf2f(pu[4]) + ALPHA_F * xb.x);
                pk.u[5] = f2bf(bf2f(pu[5]) + ALPHA_F * xb.y);
                pk.u[6] = f2bf(bf2f(pu[6]) + ALPHA_F * xb.z);
                pk.u[7] = f2bf(bf2f(pu[7]) + ALPHA_F * xb.w);
            } else {
                const float* pp = pinf + (size_t)grow * C + g * 8;
                float4 pa = *(const float4*)pp;
                float4 pb = *(const float4*)(pp + 4);
                pk.u[0] = f2bf(pa.x + ALPHA_F * xa.x);
                pk.u[1] = f2bf(pa.y + ALPHA_F * xa.y);
                pk.u[2] = f2bf(pa.z + ALPHA_F * xa.z);
                pk.u[3] = f2bf(pa.w + ALPHA_F * xa.w);
                pk.u[4] = f2bf(pb.x + ALPHA_F * xb.x);
                pk.u[5] = f2bf(pb.y + ALPHA_F * xb.y);
                pk.u[6] = f2bf(pb.z + ALPHA_F * xb.z);
                pk.u[7] = f2bf(pb.w + ALPHA_F * xb.w);
            }
        } else {
            pk.v = make_uint4(0, 0, 0, 0);
        }
        *(uint4*)&slds[r * 128 + (g ^ (r & 7)) * 8] = pk.v;
    }
    __syncthreads();

    int w    = tid >> 6;
    int lane = tid & 63;
    int l16  = lane & 15;
    int h    = lane >> 4;
    int arow = w * 16 + l16;

    f32x4 acc[8];
    #pragma unroll
    for (int t = 0; t < 8; ++t) acc[t] = (f32x4){0.f, 0.f, 0.f, 0.f};

    #pragma unroll
    for (int k0 = 0; k0 < 128; k0 += 32) {
        int ga = ((k0 >> 3) + h) ^ (arow & 7);
        bf16x8 a = *(const bf16x8*)&slds[arow * 128 + ga * 8];
        #pragma unroll
        for (int t = 0; t < 8; ++t) {
            int brow = t * 16 + l16;
            int gb = ((k0 >> 3) + h) ^ (brow & 7);
            bf16x8 b = *(const bf16x8*)&wlds[brow * 128 + gb * 8];
            acc[t] = __builtin_amdgcn_mfma_f32_16x16x32_bf16(a, b, acc[t], 0, 0, 0);
        }
    }

    #pragma unroll
    for (int t = 0; t < 8; ++t) {
        int j  = t * 16 + l16;
        float bj = BETA_F * bias[j];
        #pragma unroll
        for (int e2 = 0; e2 < 4; ++e2) {
            int grow = row0 + w * 16 + h * 4 + e2;
            if (grow < n) {
                __builtin_nontemporal_store(acc[t][e2] + bj, &out[(size_t)grow * C + j]);
            }
        }
    }
}

extern "C" void kernel_launch(void* const* d_in, const int* in_sizes, int n_in,
                              void* d_out, int out_size, void* d_ws, size_t ws_size,
                              hipStream_t stream) {
    const float* x   = (const float*)d_in[0];
    const float* x0  = (const float*)d_in[1];
    const float* W   = (const float*)d_in[2];
    const float* b   = (const float*)d_in[3];
    const int*   ei  = (const int*)d_in[4];

    int n = in_sizes[0] / C;
    int e = in_sizes[4] / 2;
    const int* src = ei;
    const int* dst = ei + e;

    int*   cnt        = (int*)d_ws;                    // n
    int*   cursor     = cnt + n;                       // n
    float* dinv       = (float*)(cursor + n);          // n
    int*   part       = (int*)(dinv + n);              // 512
    int4*  meta       = (int4*)(part + 512);           // n
    int*   sorted_src = (int*)(meta + n);              // e
    unsigned short* Vb     = (unsigned short*)(sorted_src + e);
    unsigned short* y      = Vb + C * C;               // n*C
    unsigned short* prop16 = y + (size_t)n * C;        // n*C

    size_t need = (size_t)((char*)(prop16 + (size_t)n * C) - (char*)d_ws);
    int mode = (ws_size >= need) ? 1 : 0;

    float* out = (float*)d_out;

    int nb  = (n + 255) / 256;
    int eb  = (e + 255) / 256;
    int ybg = (n * 32 + 255) / 256;

    k_init   <<<nb, 256, 0, stream>>>(W, Vb, cnt, n);
    k_hist   <<<eb, 256, 0, stream>>>(dst, cnt, e);
    k_scan_a <<<nb, 256, 0, stream>>>(cnt, part, n);
    k_scan_bc<<<nb, 256, 0, stream>>>(cnt, part, meta, cursor, dinv, n);
    k_pl_ybf <<<eb + ybg, 256, 0, stream>>>(src, dst, cursor, sorted_src, e,
                                            x, dinv, y, n, eb);
    k_gather <<<(n + 7) / 8, 256, 0, stream>>>(y, sorted_src, meta, out, prop16, mode, n);
    k_out    <<<(n + 63) / 64, 256, 0, stream>>>(out, prop16, x0, Vb, b, out, mode, n);
}

// Round 11
// 144.269 us; speedup vs baseline: 1.5144x; 1.0044x over previous
//
#include <hip/hip_runtime.h>
#include <stdint.h>

#define C 128
#define ALPHA_F 0.1f
#define ONE_MINUS_ALPHA 0.9f
// beta = log(THETA/LAYER + 1) = log(1.25)
#define BETA_F 0.22314355131420976f
#define ONE_MINUS_BETA 0.7768564486857902f

typedef __attribute__((ext_vector_type(8))) short bf16x8;
typedef __attribute__((ext_vector_type(4))) float f32x4;

__device__ inline float bf2f(unsigned short u) {
    union { unsigned int i; float f; } c;
    c.i = ((unsigned int)u) << 16;
    return c.f;
}
__device__ inline unsigned short f2bf(float f) {
    union { float f; unsigned int i; } c;
    c.f = f;
    unsigned int r = (c.i + 0x7FFFu + ((c.i >> 16) & 1u)) >> 16;  // RNE
    return (unsigned short)r;
}

// ---- init: zero cnt + V = (1-beta)*I + beta*W^T, stored Vb[j][k] bf16 ----
__global__ void k_init(const float* __restrict__ W, unsigned short* __restrict__ Vb,
                       int* __restrict__ cnt, int n) {
    int i = blockIdx.x * 256 + threadIdx.x;
    if (i < n) cnt[i] = 0;
    if (i < C * C) {
        int j = i >> 7;   // W row = output index
        int c = i & 127;  // k index
        float v = BETA_F * W[i] + ((j == c) ? ONE_MINUS_BETA : 0.f);
        Vb[i] = f2bf(v);
    }
}

// hist + rank capture: rank[i] = this edge's order among edges with same dst.
// The atomic we already pay doubles as the placement rank (no second atomic pass).
__global__ void k_hist(const int* __restrict__ dst, int* __restrict__ cnt,
                       int* __restrict__ rank, int e) {
    int i = blockIdx.x * blockDim.x + threadIdx.x;
    if (i < e) rank[i] = atomicAdd(&cnt[dst[i]], 1);
}

__global__ __launch_bounds__(256)
void k_scan_a(const int* __restrict__ cnt, int* __restrict__ part, int n) {
    __shared__ int s[256];
    int t = threadIdx.x;
    int i = blockIdx.x * 256 + t;
    s[t] = (i < n) ? cnt[i] : 0;
    __syncthreads();
    for (int off = 128; off > 0; off >>= 1) {
        if (t < off) s[t] += s[t + off];
        __syncthreads();
    }
    if (t == 0) part[blockIdx.x] = s[0];
}

// merged scan_b + scan_c: each block reduces part[0..bid-1] itself, then does
// the per-element exclusive scan; emits meta{start,len,dinv}, row_ptr, dinv.
__global__ __launch_bounds__(256)
void k_scan_bc(const int* __restrict__ cnt, const int* __restrict__ part,
               int4* __restrict__ meta, int* __restrict__ row_ptr,
               float* __restrict__ dinv, int n) {
    __shared__ int a[256];
    __shared__ int b[256];
    int t   = threadIdx.x;
    int bid = blockIdx.x;

    int local = 0;
    for (int k = t; k < bid; k += 256) local += part[k];
    a[t] = local;
    __syncthreads();
    for (int off = 128; off > 0; off >>= 1) {
        if (t < off) a[t] += a[t + off];
        __syncthreads();
    }
    int blockoff = a[0];
    __syncthreads();

    int i = bid * 256 + t;
    int v = (i < n) ? cnt[i] : 0;
    a[t] = v;
    __syncthreads();
    int* cur = a;
    int* nxt = b;
    for (int off = 1; off < 256; off <<= 1) {
        nxt[t] = cur[t] + ((t >= off) ? cur[t - off] : 0);
        __syncthreads();
        int* tmp = cur; cur = nxt; nxt = tmp;
    }
    if (i < n) {
        int rp = blockoff + cur[t] - v;
        float dv = rsqrtf((float)(v + 1));     // deg includes self-loop
        meta[i]    = make_int4(rp, v, __float_as_int(dv), 0);
        row_ptr[i] = rp;
        dinv[i]    = dv;
    }
}

// merged place + ybf: blocks [0,eb) place edges (NO atomics: row_ptr+rank);
// blocks [eb,..) build y = bf16(x * dinv).
__global__ void k_pl_ybf(const int* __restrict__ src, const int* __restrict__ dst,
                         const int* __restrict__ row_ptr, const int* __restrict__ rank,
                         int* __restrict__ sorted_src, int e,
                         const float* __restrict__ x, const float* __restrict__ dinv,
                         unsigned short* __restrict__ y, int n, int eb) {
    int bid = blockIdx.x;
    if (bid < eb) {
        int i = bid * 256 + threadIdx.x;
        if (i < e) {
            int d = dst[i];
            int pos = row_ptr[d] + rank[i];
            sorted_src[pos] = src[i];
        }
    } else {
        int t = (bid - eb) * 256 + threadIdx.x;
        int total = n * 32;
        if (t < total) {
            int i = t >> 5;
            float dv = dinv[i];
            float4 v = ((const float4*)x)[t];
            ushort4 o;
            o.x = f2bf(v.x * dv);
            o.y = f2bf(v.y * dv);
            o.z = f2bf(v.z * dv);
            o.w = f2bf(v.w * dv);
            ((ushort4*)y)[t] = o;
        }
    }
}

// ---------------- gather + alpha-blend -> s (bf16 ws or fp32 d_out) --------
// 2 nodes/wave: each half-wave (32 lanes = full 256B row) owns a node.
// meta int4 = one load for {start,len,dinv}. 8 weight-clamped y-row loads
// up-front (covers deg<=8), 4-wide batches to 32, uniform tail beyond.
__global__ __launch_bounds__(256)
void k_gather(const unsigned short* __restrict__ y, const float* __restrict__ x0,
              const int* __restrict__ sorted_src, const int4* __restrict__ meta,
              float* __restrict__ soutf, unsigned short* __restrict__ soutb,
              int mode, int n) {
    int tid  = threadIdx.x;
    int l32  = tid & 31;
    int base = tid & 32;                 // this half's lane base within the wave
    int node = blockIdx.x * 8 + (tid >> 5);
    if (node >= n) return;

    const ushort4* y4 = (const ushort4*)y;

    int4 md   = meta[node];
    int start = md.x;
    int len   = md.y;
    float dv  = __int_as_float(md.z);
    float4 xv = ((const float4*)x0)[(size_t)node * 32 + l32];

    int m = (len < 32) ? len : 32;
    int eidx = (l32 < m) ? sorted_src[start + l32] : node;  // pad = self (valid row)

    bool b1 = 1 < m, b2 = 2 < m, b3 = 3 < m;
    bool b4 = 4 < m, b5 = 5 < m, b6 = 6 < m, b7 = 7 < m;
    int s0 = __shfl(eidx, base + 0, 64);
    int s1 = __shfl(eidx, base + (b1 ? 1 : 0), 64);
    int s2 = __shfl(eidx, base + (b2 ? 2 : 0), 64);
    int s3 = __shfl(eidx, base + (b3 ? 3 : 0), 64);
    int s4 = __shfl(eidx, base + (b4 ? 4 : 0), 64);
    int s5 = __shfl(eidx, base + (b5 ? 5 : 0), 64);
    int s6 = __shfl(eidx, base + (b6 ? 6 : 0), 64);
    int s7 = __shfl(eidx, base + (b7 ? 7 : 0), 64);
    ushort4 v0 = y4[(size_t)s0 * 32 + l32];
    ushort4 v1 = y4[(size_t)s1 * 32 + l32];
    ushort4 v2 = y4[(size_t)s2 * 32 + l32];
    ushort4 v3 = y4[(size_t)s3 * 32 + l32];
    ushort4 v4 = y4[(size_t)s4 * 32 + l32];
    ushort4 v5 = y4[(size_t)s5 * 32 + l32];
    ushort4 v6 = y4[(size_t)s6 * 32 + l32];
    ushort4 v7 = y4[(size_t)s7 * 32 + l32];
    ushort4 vs = y4[(size_t)node * 32 + l32];   // self-loop row

    float w0 = (0 < m) ? 1.f : 0.f, w1 = b1 ? 1.f : 0.f, w2 = b2 ? 1.f : 0.f, w3 = b3 ? 1.f : 0.f;
    float w4 = b4 ? 1.f : 0.f, w5 = b5 ? 1.f : 0.f, w6 = b6 ? 1.f : 0.f, w7 = b7 ? 1.f : 0.f;

    float4 acc;
    acc.x = bf2f(vs.x) + w0 * bf2f(v0.x) + w1 * bf2f(v1.x) + w2 * bf2f(v2.x) + w3 * bf2f(v3.x)
                       + w4 * bf2f(v4.x) + w5 * bf2f(v5.x) + w6 * bf2f(v6.x) + w7 * bf2f(v7.x);
    acc.y = bf2f(vs.y) + w0 * bf2f(v0.y) + w1 * bf2f(v1.y) + w2 * bf2f(v2.y) + w3 * bf2f(v3.y)
                       + w4 * bf2f(v4.y) + w5 * bf2f(v5.y) + w6 * bf2f(v6.y) + w7 * bf2f(v7.y);
    acc.z = bf2f(vs.z) + w0 * bf2f(v0.z) + w1 * bf2f(v1.z) + w2 * bf2f(v2.z) + w3 * bf2f(v3.z)
                       + w4 * bf2f(v4.z) + w5 * bf2f(v5.z) + w6 * bf2f(v6.z) + w7 * bf2f(v7.z);
    acc.w = bf2f(vs.w) + w0 * bf2f(v0.w) + w1 * bf2f(v1.w) + w2 * bf2f(v2.w) + w3 * bf2f(v3.w)
                       + w4 * bf2f(v4.w) + w5 * bf2f(v5.w) + w6 * bf2f(v6.w) + w7 * bf2f(v7.w);

    for (int j = 8; j < m; j += 4) {     // 9..32 incident edges
        bool c1 = (j + 1) < m, c2 = (j + 2) < m, c3 = (j + 3) < m;
        int t0 = __shfl(eidx, base + j, 64);
        int t1 = __shfl(eidx, base + (c1 ? j + 1 : j), 64);
        int t2 = __shfl(eidx, base + (c2 ? j + 2 : j), 64);
        int t3 = __shfl(eidx, base + (c3 ? j + 3 : j), 64);
        ushort4 u0 = y4[(size_t)t0 * 32 + l32];
        ushort4 u1 = y4[(size_t)t1 * 32 + l32];
        ushort4 u2 = y4[(size_t)t2 * 32 + l32];
        ushort4 u3 = y4[(size_t)t3 * 32 + l32];
        float q1 = c1 ? 1.f : 0.f, q2 = c2 ? 1.f : 0.f, q3 = c3 ? 1.f : 0.f;
        acc.x += bf2f(u0.x) + q1 * bf2f(u1.x) + q2 * bf2f(u2.x) + q3 * bf2f(u3.x);
        acc.y += bf2f(u0.y) + q1 * bf2f(u1.y) + q2 * bf2f(u2.y) + q3 * bf2f(u3.y);
        acc.z += bf2f(u0.z) + q1 * bf2f(u1.z) + q2 * bf2f(u2.z) + q3 * bf2f(u3.z);
        acc.w += bf2f(u0.w) + q1 * bf2f(u1.w) + q2 * bf2f(u2.w) + q3 * bf2f(u3.w);
    }

    for (int j = 32; j < len; ++j) {     // rare: degree > 32 (uniform broadcast)
        int t0 = sorted_src[start + j];
        ushort4 u0 = y4[(size_t)t0 * 32 + l32];
        acc.x += bf2f(u0.x);
        acc.y += bf2f(u0.y);
        acc.z += bf2f(u0.z);
        acc.w += bf2f(u0.w);
    }

    float4 s;
    s.x = ONE_MINUS_ALPHA * (dv * acc.x) + ALPHA_F * xv.x;
    s.y = ONE_MINUS_ALPHA * (dv * acc.y) + ALPHA_F * xv.y;
    s.z = ONE_MINUS_ALPHA * (dv * acc.z) + ALPHA_F * xv.z;
    s.w = ONE_MINUS_ALPHA * (dv * acc.w) + ALPHA_F * xv.w;

    if (mode) {
        unsigned long long pk =
            (unsigned long long)f2bf(s.x)
          | ((unsigned long long)f2bf(s.y) << 16)
          | ((unsigned long long)f2bf(s.z) << 32)
          | ((unsigned long long)f2bf(s.w) << 48);
        __builtin_nontemporal_store(
            pk, (unsigned long long*)(soutb + (size_t)node * C + l32 * 4));
    } else {
        ((float4*)soutf)[(size_t)node * 32 + l32] = s;
    }
}

// ---------------- no-LDS MFMA GEMM: out = s @ V + beta*b ----------------
// V folds the (1-beta)*s blend. A-fragments straight from global sb16
// (L3-resident), B-fragments straight from Vb (32 KB, L1/L2-resident).
// No LDS, no barrier -> occupancy limited only by VGPRs; pure stream.
// Layouts (m89/m91): A row=lane&15 (own row), k=8*(lane>>4)+i;
// B col j=t*16+(lane&15) via Vb[j][k] contiguous; D col=lane&15,
// row=4*(lane>>4)+reg.
__global__ __launch_bounds__(256)
void k_out(const float* __restrict__ pinf, const unsigned short* __restrict__ pinb,
           const unsigned short* __restrict__ Vb, const float* __restrict__ bias,
           float* __restrict__ out, int mode, int n) {
    int tid  = threadIdx.x;
    int w    = tid >> 6;
    int lane = tid & 63;
    int l16  = lane & 15;
    int h    = lane >> 4;
    int row0 = blockIdx.x * 64;
    int arow = row0 + w * 16 + l16;
    bool rowok = arow < n;

    f32x4 acc[8];
    #pragma unroll
    for (int t = 0; t < 8; ++t) acc[t] = (f32x4){0.f, 0.f, 0.f, 0.f};

    #pragma unroll
    for (int k0 = 0; k0 < 128; k0 += 32) {
        bf16x8 a;
        if (rowok) {
            if (mode) {
                a = *(const bf16x8*)(pinb + (size_t)arow * C + k0 + h * 8);
            } else {
                const float* ap = pinf + (size_t)arow * C + k0 + h * 8;
                float4 aa = *(const float4*)ap;
                float4 ab = *(const float4*)(ap + 4);
                union { unsigned short u[8]; bf16x8 v; } pk;
                pk.u[0] = f2bf(aa.x); pk.u[1] = f2bf(aa.y);
                pk.u[2] = f2bf(aa.z); pk.u[3] = f2bf(aa.w);
                pk.u[4] = f2bf(ab.x); pk.u[5] = f2bf(ab.y);
                pk.u[6] = f2bf(ab.z); pk.u[7] = f2bf(ab.w);
                a = pk.v;
            }
        } else {
            a = (bf16x8){0, 0, 0, 0, 0, 0, 0, 0};
        }
        #pragma unroll
        for (int t = 0; t < 8; ++t) {
            bf16x8 b = *(const bf16x8*)(Vb + (size_t)(t * 16 + l16) * C + k0 + h * 8);
            acc[t] = __builtin_amdgcn_mfma_f32_16x16x32_bf16(a, b, acc[t], 0, 0, 0);
        }
    }

    #pragma unroll
    for (int t = 0; t < 8; ++t) {
        int j  = t * 16 + l16;
        float bj = BETA_F * bias[j];
        #pragma unroll
        for (int e2 = 0; e2 < 4; ++e2) {
            int grow = row0 + w * 16 + h * 4 + e2;
            if (grow < n) {
                __builtin_nontemporal_store(acc[t][e2] + bj, &out[(size_t)grow * C + j]);
            }
        }
    }
}

extern "C" void kernel_launch(void* const* d_in, const int* in_sizes, int n_in,
                              void* d_out, int out_size, void* d_ws, size_t ws_size,
                              hipStream_t stream) {
    const float* x   = (const float*)d_in[0];
    const float* x0  = (const float*)d_in[1];
    const float* W   = (const float*)d_in[2];
    const float* b   = (const float*)d_in[3];
    const int*   ei  = (const int*)d_in[4];

    int n = in_sizes[0] / C;
    int e = in_sizes[4] / 2;
    const int* src = ei;
    const int* dst = ei + e;

    int*   cnt        = (int*)d_ws;                    // n
    float* dinv       = (float*)(cnt + n);             // n
    int*   part       = (int*)(dinv + n);              // 512
    int4*  meta       = (int4*)(part + 512);           // n (16B-aligned: 2n+512 ints)
    int*   row_ptr    = (int*)(meta + n);              // n
    int*   rank       = row_ptr + n;                   // e
    int*   sorted_src = rank + e;                      // e
    unsigned short* Vb   = (unsigned short*)(sorted_src + e);
    unsigned short* y    = Vb + C * C;                 // n*C
    unsigned short* sb16 = y + (size_t)n * C;          // n*C

    size_t need = (size_t)((char*)(sb16 + (size_t)n * C) - (char*)d_ws);
    int mode = (ws_size >= need) ? 1 : 0;

    float* out = (float*)d_out;

    int nb  = (n + 255) / 256;
    int eb  = (e + 255) / 256;
    int ybg = (n * 32 + 255) / 256;

    k_init   <<<nb, 256, 0, stream>>>(W, Vb, cnt, n);
    k_hist   <<<eb, 256, 0, stream>>>(dst, cnt, rank, e);
    k_scan_a <<<nb, 256, 0, stream>>>(cnt, part, n);
    k_scan_bc<<<nb, 256, 0, stream>>>(cnt, part, meta, row_ptr, dinv, n);
    k_pl_ybf <<<eb + ybg, 256, 0, stream>>>(src, dst, row_ptr, rank, sorted_src, e,
                                            x, dinv, y, n, eb);
    k_gather <<<(n + 7) / 8, 256, 0, stream>>>(y, x0, sorted_src, meta,
                                               out, sb16, mode, n);
    k_out    <<<(n + 63) / 64, 256, 0, stream>>>(out, sb16, Vb, b, out, mode, n);
}

// Round 12
// 126.253 us; speedup vs baseline: 1.7305x; 1.1427x over previous
//
#include <hip/hip_runtime.h>
#include <stdint.h>

#define C 128
#define ALPHA_F 0.1f
#define ONE_MINUS_ALPHA 0.9f
// beta = log(THETA/LAYER + 1) = log(1.25)
#define BETA_F 0.22314355131420976f
#define ONE_MINUS_BETA 0.7768564486857902f

typedef __attribute__((ext_vector_type(8))) short bf16x8;
typedef __attribute__((ext_vector_type(4))) float f32x4;

__device__ inline float bf2f(unsigned short u) {
    union { unsigned int i; float f; } c;
    c.i = ((unsigned int)u) << 16;
    return c.f;
}
__device__ inline unsigned short f2bf(float f) {
    union { float f; unsigned int i; } c;
    c.f = f;
    unsigned int r = (c.i + 0x7FFFu + ((c.i >> 16) & 1u)) >> 16;  // RNE
    return (unsigned short)r;
}

// ---- init: zero cnt + V = (1-beta)*I + beta*W^T, stored Vb[j][k] bf16 ----
__global__ void k_init(const float* __restrict__ W, unsigned short* __restrict__ Vb,
                       int* __restrict__ cnt, int n) {
    int i = blockIdx.x * 256 + threadIdx.x;
    if (i < n) cnt[i] = 0;
    if (i < C * C) {
        int j = i >> 7;   // W row = output index
        int c = i & 127;  // k index
        float v = BETA_F * W[i] + ((j == c) ? ONE_MINUS_BETA : 0.f);
        Vb[i] = f2bf(v);
    }
}

// hist + rank capture: the atomic doubles as the placement rank.
__global__ void k_hist(const int* __restrict__ dst, int* __restrict__ cnt,
                       int* __restrict__ rank, int e) {
    int i = blockIdx.x * blockDim.x + threadIdx.x;
    if (i < e) rank[i] = atomicAdd(&cnt[dst[i]], 1);
}

__global__ __launch_bounds__(256)
void k_scan_a(const int* __restrict__ cnt, int* __restrict__ part, int n) {
    __shared__ int s[256];
    int t = threadIdx.x;
    int i = blockIdx.x * 256 + t;
    s[t] = (i < n) ? cnt[i] : 0;
    __syncthreads();
    for (int off = 128; off > 0; off >>= 1) {
        if (t < off) s[t] += s[t + off];
        __syncthreads();
    }
    if (t == 0) part[blockIdx.x] = s[0];
}

// merged scan_b + scan_c
__global__ __launch_bounds__(256)
void k_scan_bc(const int* __restrict__ cnt, const int* __restrict__ part,
               int4* __restrict__ meta, int* __restrict__ row_ptr,
               float* __restrict__ dinv, int n) {
    __shared__ int a[256];
    __shared__ int b[256];
    int t   = threadIdx.x;
    int bid = blockIdx.x;

    int local = 0;
    for (int k = t; k < bid; k += 256) local += part[k];
    a[t] = local;
    __syncthreads();
    for (int off = 128; off > 0; off >>= 1) {
        if (t < off) a[t] += a[t + off];
        __syncthreads();
    }
    int blockoff = a[0];
    __syncthreads();

    int i = bid * 256 + t;
    int v = (i < n) ? cnt[i] : 0;
    a[t] = v;
    __syncthreads();
    int* cur = a;
    int* nxt = b;
    for (int off = 1; off < 256; off <<= 1) {
        nxt[t] = cur[t] + ((t >= off) ? cur[t - off] : 0);
        __syncthreads();
        int* tmp = cur; cur = nxt; nxt = tmp;
    }
    if (i < n) {
        int rp = blockoff + cur[t] - v;
        float dv = rsqrtf((float)(v + 1));     // deg includes self-loop
        meta[i]    = make_int4(rp, v, __float_as_int(dv), 0);
        row_ptr[i] = rp;
        dinv[i]    = dv;
    }
}

// merged place + ybf: blocks [0,eb) place edges (no atomics); rest build y.
__global__ void k_pl_ybf(const int* __restrict__ src, const int* __restrict__ dst,
                         const int* __restrict__ row_ptr, const int* __restrict__ rank,
                         int* __restrict__ sorted_src, int e,
                         const float* __restrict__ x, const float* __restrict__ dinv,
                         unsigned short* __restrict__ y, int n, int eb) {
    int bid = blockIdx.x;
    if (bid < eb) {
        int i = bid * 256 + threadIdx.x;
        if (i < e) {
            int d = dst[i];
            int pos = row_ptr[d] + rank[i];
            sorted_src[pos] = src[i];
        }
    } else {
        int t = (bid - eb) * 256 + threadIdx.x;
        int total = n * 32;
        if (t < total) {
            int i = t >> 5;
            float dv = dinv[i];
            float4 v = ((const float4*)x)[t];
            ushort4 o;
            o.x = f2bf(v.x * dv);
            o.y = f2bf(v.y * dv);
            o.z = f2bf(v.z * dv);
            o.w = f2bf(v.w * dv);
            ((ushort4*)y)[t] = o;
        }
    }
}

// ---------------- gather + alpha-blend -> s (bf16 ws or fp32 d_out) --------
__global__ __launch_bounds__(256)
void k_gather(const unsigned short* __restrict__ y, const float* __restrict__ x0,
              const int* __restrict__ sorted_src, const int4* __restrict__ meta,
              float* __restrict__ soutf, unsigned short* __restrict__ soutb,
              int mode, int n) {
    int tid  = threadIdx.x;
    int l32  = tid & 31;
    int base = tid & 32;
    int node = blockIdx.x * 8 + (tid >> 5);
    if (node >= n) return;

    const ushort4* y4 = (const ushort4*)y;

    int4 md   = meta[node];
    int start = md.x;
    int len   = md.y;
    float dv  = __int_as_float(md.z);
    float4 xv = ((const float4*)x0)[(size_t)node * 32 + l32];

    int m = (len < 32) ? len : 32;
    int eidx = (l32 < m) ? sorted_src[start + l32] : node;  // pad = self

    bool b1 = 1 < m, b2 = 2 < m, b3 = 3 < m;
    bool b4 = 4 < m, b5 = 5 < m, b6 = 6 < m, b7 = 7 < m;
    int s0 = __shfl(eidx, base + 0, 64);
    int s1 = __shfl(eidx, base + (b1 ? 1 : 0), 64);
    int s2 = __shfl(eidx, base + (b2 ? 2 : 0), 64);
    int s3 = __shfl(eidx, base + (b3 ? 3 : 0), 64);
    int s4 = __shfl(eidx, base + (b4 ? 4 : 0), 64);
    int s5 = __shfl(eidx, base + (b5 ? 5 : 0), 64);
    int s6 = __shfl(eidx, base + (b6 ? 6 : 0), 64);
    int s7 = __shfl(eidx, base + (b7 ? 7 : 0), 64);
    ushort4 v0 = y4[(size_t)s0 * 32 + l32];
    ushort4 v1 = y4[(size_t)s1 * 32 + l32];
    ushort4 v2 = y4[(size_t)s2 * 32 + l32];
    ushort4 v3 = y4[(size_t)s3 * 32 + l32];
    ushort4 v4 = y4[(size_t)s4 * 32 + l32];
    ushort4 v5 = y4[(size_t)s5 * 32 + l32];
    ushort4 v6 = y4[(size_t)s6 * 32 + l32];
    ushort4 v7 = y4[(size_t)s7 * 32 + l32];
    ushort4 vs = y4[(size_t)node * 32 + l32];   // self-loop row

    float w0 = (0 < m) ? 1.f : 0.f, w1 = b1 ? 1.f : 0.f, w2 = b2 ? 1.f : 0.f, w3 = b3 ? 1.f : 0.f;
    float w4 = b4 ? 1.f : 0.f, w5 = b5 ? 1.f : 0.f, w6 = b6 ? 1.f : 0.f, w7 = b7 ? 1.f : 0.f;

    float4 acc;
    acc.x = bf2f(vs.x) + w0 * bf2f(v0.x) + w1 * bf2f(v1.x) + w2 * bf2f(v2.x) + w3 * bf2f(v3.x)
                       + w4 * bf2f(v4.x) + w5 * bf2f(v5.x) + w6 * bf2f(v6.x) + w7 * bf2f(v7.x);
    acc.y = bf2f(vs.y) + w0 * bf2f(v0.y) + w1 * bf2f(v1.y) + w2 * bf2f(v2.y) + w3 * bf2f(v3.y)
                       + w4 * bf2f(v4.y) + w5 * bf2f(v5.y) + w6 * bf2f(v6.y) + w7 * bf2f(v7.y);
    acc.z = bf2f(vs.z) + w0 * bf2f(v0.z) + w1 * bf2f(v1.z) + w2 * bf2f(v2.z) + w3 * bf2f(v3.z)
                       + w4 * bf2f(v4.z) + w5 * bf2f(v5.z) + w6 * bf2f(v6.z) + w7 * bf2f(v7.z);
    acc.w = bf2f(vs.w) + w0 * bf2f(v0.w) + w1 * bf2f(v1.w) + w2 * bf2f(v2.w) + w3 * bf2f(v3.w)
                       + w4 * bf2f(v4.w) + w5 * bf2f(v5.w) + w6 * bf2f(v6.w) + w7 * bf2f(v7.w);

    for (int j = 8; j < m; j += 4) {
        bool c1 = (j + 1) < m, c2 = (j + 2) < m, c3 = (j + 3) < m;
        int t0 = __shfl(eidx, base + j, 64);
        int t1 = __shfl(eidx, base + (c1 ? j + 1 : j), 64);
        int t2 = __shfl(eidx, base + (c2 ? j + 2 : j), 64);
        int t3 = __shfl(eidx, base + (c3 ? j + 3 : j), 64);
        ushort4 u0 = y4[(size_t)t0 * 32 + l32];
        ushort4 u1 = y4[(size_t)t1 * 32 + l32];
        ushort4 u2 = y4[(size_t)t2 * 32 + l32];
        ushort4 u3 = y4[(size_t)t3 * 32 + l32];
        float q1 = c1 ? 1.f : 0.f, q2 = c2 ? 1.f : 0.f, q3 = c3 ? 1.f : 0.f;
        acc.x += bf2f(u0.x) + q1 * bf2f(u1.x) + q2 * bf2f(u2.x) + q3 * bf2f(u3.x);
        acc.y += bf2f(u0.y) + q1 * bf2f(u1.y) + q2 * bf2f(u2.y) + q3 * bf2f(u3.y);
        acc.z += bf2f(u0.z) + q1 * bf2f(u1.z) + q2 * bf2f(u2.z) + q3 * bf2f(u3.z);
        acc.w += bf2f(u0.w) + q1 * bf2f(u1.w) + q2 * bf2f(u2.w) + q3 * bf2f(u3.w);
    }

    for (int j = 32; j < len; ++j) {     // rare: degree > 32
        int t0 = sorted_src[start + j];
        ushort4 u0 = y4[(size_t)t0 * 32 + l32];
        acc.x += bf2f(u0.x);
        acc.y += bf2f(u0.y);
        acc.z += bf2f(u0.z);
        acc.w += bf2f(u0.w);
    }

    float4 s;
    s.x = ONE_MINUS_ALPHA * (dv * acc.x) + ALPHA_F * xv.x;
    s.y = ONE_MINUS_ALPHA * (dv * acc.y) + ALPHA_F * xv.y;
    s.z = ONE_MINUS_ALPHA * (dv * acc.z) + ALPHA_F * xv.z;
    s.w = ONE_MINUS_ALPHA * (dv * acc.w) + ALPHA_F * xv.w;

    if (mode) {
        unsigned long long pk =
            (unsigned long long)f2bf(s.x)
          | ((unsigned long long)f2bf(s.y) << 16)
          | ((unsigned long long)f2bf(s.z) << 32)
          | ((unsigned long long)f2bf(s.w) << 48);
        __builtin_nontemporal_store(
            pk, (unsigned long long*)(soutb + (size_t)node * C + l32 * 4));
    } else {
        ((float4*)soutf)[(size_t)node * 32 + l32] = s;
    }
}

// ---------------- MFMA GEMM (LDS-staged): out = s @ V + beta*b ----------------
// V folds the (1-beta)*s blend. Both operands staged in LDS with 16B-granule
// XOR swizzle (g ^= row&7) -> conflict-free ds_read_b128 for MFMA fragments.
// This beats global B-reads: 32 scattered vector loads/wave -> LDS reads.
__global__ __launch_bounds__(256)
void k_out(const float* __restrict__ sinf, const unsigned short* __restrict__ sinb,
           const unsigned short* __restrict__ Vb, const float* __restrict__ bias,
           float* __restrict__ out, int mode, int n) {
    __shared__ unsigned short wlds[128 * 128];  // 32 KB
    __shared__ unsigned short slds[64 * 128];   // 16 KB

    int tid  = threadIdx.x;
    int row0 = blockIdx.x * 64;

    const uint4* Vb16 = (const uint4*)Vb;
    for (int i = tid; i < 2048; i += 256) {
        int j = i >> 4;
        int g = i & 15;
        uint4 v = Vb16[i];
        *(uint4*)&wlds[j * 128 + (g ^ (j & 7)) * 8] = v;
    }

    if (mode) {
        const uint4* sb16 = (const uint4*)sinb;
        for (int i = tid; i < 1024; i += 256) {
            int r = i >> 4;
            int g = i & 15;
            int grow = row0 + r;
            uint4 v = make_uint4(0, 0, 0, 0);
            if (grow < n) v = sb16[(size_t)grow * 16 + g];
            *(uint4*)&slds[r * 128 + (g ^ (r & 7)) * 8] = v;
        }
    } else {
        for (int i = tid; i < 1024; i += 256) {
            int r = i >> 4;
            int g = i & 15;
            int grow = row0 + r;
            union { unsigned short u[8]; uint4 v; } pk;
            if (grow < n) {
                const float* p = sinf + (size_t)grow * C + g * 8;
                float4 aa = *(const float4*)p;
                float4 bb = *(const float4*)(p + 4);
                pk.u[0] = f2bf(aa.x); pk.u[1] = f2bf(aa.y);
                pk.u[2] = f2bf(aa.z); pk.u[3] = f2bf(aa.w);
                pk.u[4] = f2bf(bb.x); pk.u[5] = f2bf(bb.y);
                pk.u[6] = f2bf(bb.z); pk.u[7] = f2bf(bb.w);
            } else {
                pk.v = make_uint4(0, 0, 0, 0);
            }
            *(uint4*)&slds[r * 128 + (g ^ (r & 7)) * 8] = pk.v;
        }
    }
    __syncthreads();

    int w    = tid >> 6;
    int lane = tid & 63;
    int l16  = lane & 15;
    int h    = lane >> 4;
    int arow = w * 16 + l16;

    f32x4 acc[8];
    #pragma unroll
    for (int t = 0; t < 8; ++t) acc[t] = (f32x4){0.f, 0.f, 0.f, 0.f};

    #pragma unroll
    for (int k0 = 0; k0 < 128; k0 += 32) {
        int ga = ((k0 >> 3) + h) ^ (arow & 7);
        bf16x8 a = *(const bf16x8*)&slds[arow * 128 + ga * 8];
        #pragma unroll
        for (int t = 0; t < 8; ++t) {
            int brow = t * 16 + l16;
            int gb = ((k0 >> 3) + h) ^ (brow & 7);
            bf16x8 b = *(const bf16x8*)&wlds[brow * 128 + gb * 8];
            acc[t] = __builtin_amdgcn_mfma_f32_16x16x32_bf16(a, b, acc[t], 0, 0, 0);
        }
    }

    #pragma unroll
    for (int t = 0; t < 8; ++t) {
        int j  = t * 16 + l16;
        float bj = BETA_F * bias[j];
        #pragma unroll
        for (int e2 = 0; e2 < 4; ++e2) {
            int grow = row0 + w * 16 + h * 4 + e2;
            if (grow < n) {
                __builtin_nontemporal_store(acc[t][e2] + bj, &out[(size_t)grow * C + j]);
            }
        }
    }
}

extern "C" void kernel_launch(void* const* d_in, const int* in_sizes, int n_in,
                              void* d_out, int out_size, void* d_ws, size_t ws_size,
                              hipStream_t stream) {
    const float* x   = (const float*)d_in[0];
    const float* x0  = (const float*)d_in[1];
    const float* W   = (const float*)d_in[2];
    const float* b   = (const float*)d_in[3];
    const int*   ei  = (const int*)d_in[4];

    int n = in_sizes[0] / C;
    int e = in_sizes[4] / 2;
    const int* src = ei;
    const int* dst = ei + e;

    int*   cnt        = (int*)d_ws;                    // n
    float* dinv       = (float*)(cnt + n);             // n
    int*   part       = (int*)(dinv + n);              // 512
    int4*  meta       = (int4*)(part + 512);           // n (16B aligned)
    int*   row_ptr    = (int*)(meta + n);              // n
    int*   rank       = row_ptr + n;                   // e
    int*   sorted_src = rank + e;                      // e
    unsigned short* Vb   = (unsigned short*)(sorted_src + e);
    unsigned short* y    = Vb + C * C;                 // n*C
    unsigned short* sb16 = y + (size_t)n * C;          // n*C

    size_t need = (size_t)((char*)(sb16 + (size_t)n * C) - (char*)d_ws);
    int mode = (ws_size >= need) ? 1 : 0;

    float* out = (float*)d_out;

    int nb  = (n + 255) / 256;
    int eb  = (e + 255) / 256;
    int ybg = (n * 32 + 255) / 256;

    k_init   <<<nb, 256, 0, stream>>>(W, Vb, cnt, n);
    k_hist   <<<eb, 256, 0, stream>>>(dst, cnt, rank, e);
    k_scan_a <<<nb, 256, 0, stream>>>(cnt, part, n);
    k_scan_bc<<<nb, 256, 0, stream>>>(cnt, part, meta, row_ptr, dinv, n);
    k_pl_ybf <<<eb + ybg, 256, 0, stream>>>(src, dst, row_ptr, rank, sorted_src, e,
                                            x, dinv, y, n, eb);
    k_gather <<<(n + 7) / 8, 256, 0, stream>>>(y, x0, sorted_src, meta,
                                               out, sb16, mode, n);
    k_out    <<<(n + 63) / 64, 256, 0, stream>>>(out, sb16, Vb, b, out, mode, n);
}